// Round 3
// baseline (369.899 us; speedup 1.0000x reference)
//
#include <hip/hip_runtime.h>
#include <hip/hip_bf16.h>

#define L_TOK 8192
#define NCh 512   // scan chunks
#define CLh 16    // chunk length
#define NSEG 8    // segments for chunk-combine
#define CPS (NCh / NSEG)   // chunks per segment = 64
#define LOG2E 1.44269504088896f

typedef short bf16x8 __attribute__((ext_vector_type(8)));
typedef float f32x4 __attribute__((ext_vector_type(4)));

static __device__ __forceinline__ float nexp2(float x) {
#if __has_builtin(__builtin_amdgcn_exp2f)
    return __builtin_amdgcn_exp2f(x);
#else
    return exp2f(x);
#endif
}
static __device__ __forceinline__ float sigm(float x) {
    return 1.f / (1.f + nexp2(-x * LOG2E));
}
static __device__ __forceinline__ ushort f2bf(float x) {
    union { float f; uint u; } v; v.f = x;
    uint r = v.u + 0x7fffu + ((v.u >> 16) & 1u);
    return (ushort)(r >> 16);
}
static __device__ __forceinline__ float bf2f(ushort h) {
    union { float f; uint u; } v; v.u = ((uint)h) << 16;
    return v.f;
}
static __device__ __forceinline__ void f2hl(float x, ushort* hi, ushort* lo) {
    ushort h = f2bf(x);
    *hi = h;
    *lo = f2bf(x - bf2f(h));
}

// weight regions in wH/wL (ushort elems), all K-major [n][k]:
#define W_PE   0
#define W_WIN  16384
#define W_WOUT 81920
#define W_PU   114688
#define W_PROJ 131072
#define W_TOT  212992

// ---------------------------------------------------------------------------
// prep: weights -> bf16 hi/lo (with transposes + Wx@Wdt fusion) ; maskpool
__global__ __launch_bounds__(256) void prep_k(const float* __restrict__ pe_w, const float* __restrict__ Win,
                                              const float* __restrict__ Wx, const float* __restrict__ Wdt,
                                              const float* __restrict__ Wout, const float* __restrict__ pu_w,
                                              const float* __restrict__ mask,
                                              ushort* __restrict__ wH, ushort* __restrict__ wL,
                                              float* __restrict__ mbuf) {
    int b = blockIdx.x;
    if (b >= 832) {  // maskpool
        int l = (b - 832) * 256 + threadIdx.x;
        int xg = l >> 8, yg = (l >> 3) & 31, zg = l & 7;
        float s = 0.f;
        for (int i2 = 0; i2 < 2; ++i2)
            for (int j2 = 0; j2 < 2; ++j2)
                for (int k2 = 0; k2 < 2; ++k2)
                    s += mask[(2 * xg + i2) * 1024 + (2 * yg + j2) * 16 + 2 * zg + k2];
        s *= 0.125f;
        mbuf[l] = fminf(fmaxf(s, 0.f), 1.f);
        return;
    }
    int i = b * 256 + threadIdx.x;  // < 212992
    float v;
    if (i < 16384) {
        v = pe_w[i];
    } else if (i < 81920) {
        int j = i - 16384; int n = j >> 7, k = j & 127;
        v = Win[k * 512 + n];
    } else if (i < 114688) {
        int j = i - 81920; int n = j >> 8, k = j & 255;
        v = Wout[k * 128 + n];
    } else if (i < 131072) {
        int j = i - 114688; int n = j >> 7, k = j & 127;
        v = pu_w[k * 128 + n];
    } else {
        int j = i - 131072; int n = j >> 8, k = j & 255;
        if (n < 256) {
            float s = 0.f;
#pragma unroll
            for (int r = 0; r < 8; ++r) s += Wx[k * 40 + r] * Wdt[r * 256 + n];
            v = s;
        } else if (n < 288) {
            v = Wx[k * 40 + 8 + (n - 256)];
        } else {
            v = 0.f;
        }
    }
    ushort h, lo; f2hl(v, &h, &lo);
    wH[i] = h; wL[i] = lo;
}

// ---------------------------------------------------------------------------
// fused: gather (LDS-staged, coalesced) -> embed GEMM (+pe_b+cond) -> LN2
// tile 16 x 128 (full N), 512 blocks, 256 threads.
__global__ __launch_bounds__(256) void embed_ln_k(const float* __restrict__ ks,
                                                  const ushort* __restrict__ wH, const ushort* __restrict__ wL,
                                                  const float* __restrict__ pe_b, const float* __restrict__ cond_band,
                                                  const float* __restrict__ cond_rad, const float* __restrict__ cond_mask,
                                                  const float* __restrict__ mbuf,
                                                  const float* __restrict__ ln_g, const float* __restrict__ ln_b,
                                                  const float* __restrict__ fn_g, const float* __restrict__ fn_b,
                                                  float* __restrict__ h_,
                                                  ushort* __restrict__ hnH, ushort* __restrict__ hnL) {
    __shared__ __align__(16) char smem[50176];
    ushort (*AsH)[72] = (ushort(*)[72])(smem);             // 16x72
    ushort (*AsL)[72] = (ushort(*)[72])(smem + 2304);
    ushort (*BsH)[72] = (ushort(*)[72])(smem + 4608);      // 128x72
    ushort (*BsL)[72] = (ushort(*)[72])(smem + 23040);     // ..41472
    float*  ksb       = (float*)(smem + 41472);            // 2176 floats (128 segs x 17)
    float  (*Cs)[132] = (float(*)[132])(smem);             // 16x132 (reuse after MFMA)

    const int tid = threadIdx.x;
    const int lane = tid & 63, wn = tid >> 6;
    const int ln = lane & 15, q = lane >> 4;
    const int mb = blockIdx.x * 16;
    const int xg = mb >> 8, yg0 = (mb >> 3) & 31;

    // coalesced stage of the block's kspace footprint:
    for (int v = tid; v < 512; v += 256) {
        int seg = v >> 2, zq = v & 3;
        int cc = seg >> 3, i2 = (seg >> 2) & 1, yy = seg & 3;
        float4 t4 = *(const float4*)&ks[cc * 65536 + (2 * xg + i2) * 1024 + (2 * yg0 + yy) * 16 + zq * 4];
        int la = seg * 17 + zq * 4;
        ksb[la] = t4.x; ksb[la + 1] = t4.y; ksb[la + 2] = t4.z; ksb[la + 3] = t4.w;
    }

    f32x4 acc[2];
    acc[0] = (f32x4){0.f, 0.f, 0.f, 0.f};
    acc[1] = (f32x4){0.f, 0.f, 0.f, 0.f};

    for (int kc = 0; kc < 128; kc += 64) {
        __syncthreads();
        for (int u = tid; u < 1024; u += 256) {
            int r = u >> 6, kk = u & 63;
            int k = kc + kk;
            int cc = k >> 3, ijk = k & 7;
            int i2 = (ijk >> 2) & 1, j2 = (ijk >> 1) & 1, k2 = ijk & 1;
            int seg = (cc * 2 + i2) * 4 + (r >> 3) * 2 + j2;
            float v = ksb[seg * 17 + (r & 7) * 2 + k2];
            ushort hh, ll; f2hl(v, &hh, &ll);
            AsH[r][kk] = hh; AsL[r][kk] = ll;
        }
        for (int u = tid; u < 1024; u += 256) {
            int n = u >> 3, g = u & 7;
            *(uint4*)&BsH[n][g * 8] = *(const uint4*)&wH[W_PE + n * 128 + kc + g * 8];
            *(uint4*)&BsL[n][g * 8] = *(const uint4*)&wL[W_PE + n * 128 + kc + g * 8];
        }
        __syncthreads();
#pragma unroll
        for (int ks_ = 0; ks_ < 64; ks_ += 32) {
            const int kk = ks_ + q * 8;
            bf16x8 ah = *(const bf16x8*)&AsH[ln][kk];
            bf16x8 al = *(const bf16x8*)&AsL[ln][kk];
#pragma unroll
            for (int cb = 0; cb < 2; ++cb) {
                bf16x8 bh = *(const bf16x8*)&BsH[wn * 32 + cb * 16 + ln][kk];
                bf16x8 bl = *(const bf16x8*)&BsL[wn * 32 + cb * 16 + ln][kk];
                acc[cb] = __builtin_amdgcn_mfma_f32_16x16x32_bf16(ah, bh, acc[cb], 0, 0, 0);
                acc[cb] = __builtin_amdgcn_mfma_f32_16x16x32_bf16(ah, bl, acc[cb], 0, 0, 0);
                acc[cb] = __builtin_amdgcn_mfma_f32_16x16x32_bf16(al, bh, acc[cb], 0, 0, 0);
            }
        }
    }
    __syncthreads();
#pragma unroll
    for (int cb = 0; cb < 2; ++cb) {
#pragma unroll
        for (int r = 0; r < 4; ++r) {
            int row = q * 4 + r;
            int col = wn * 32 + cb * 16 + ln;
            int l = mb + row;
            float rho = (float)l * (1.0f / 8191.0f);
            int band = min(7, (int)(rho * 8.0f));
            Cs[row][col] = acc[cb][r] + pe_b[col] + cond_band[band * 128 + col]
                           + rho * cond_rad[col] + mbuf[l] * cond_mask[col];
        }
    }
    __syncthreads();
    {
        int row = tid >> 4, j = tid & 15;
        int l = mb + row;
        float v8[8];
        float s = 0.f, s2 = 0.f;
#pragma unroll
        for (int i = 0; i < 8; ++i) {
            float v = Cs[row][j * 8 + i];
            v8[i] = v; s += v; s2 += v * v;
        }
#pragma unroll
        for (int o = 1; o < 16; o <<= 1) { s += __shfl_xor(s, o, 16); s2 += __shfl_xor(s2, o, 16); }
        float mu = s * (1.f / 128.f);
        float var = s2 * (1.f / 128.f) - mu * mu;
        float rstd = rsqrtf(fmaxf(var, 0.f) + 1e-5f);
        float hv[8];
        s = 0.f; s2 = 0.f;
#pragma unroll
        for (int i = 0; i < 8; ++i) {
            int col = j * 8 + i;
            float h = (v8[i] - mu) * rstd * ln_g[col] + ln_b[col];
            hv[i] = h; s += h; s2 += h * h;
        }
#pragma unroll
        for (int i = 0; i < 8; i += 4)
            *(float4*)&h_[(size_t)l * 128 + j * 8 + i] = make_float4(hv[i], hv[i + 1], hv[i + 2], hv[i + 3]);
#pragma unroll
        for (int o = 1; o < 16; o <<= 1) { s += __shfl_xor(s, o, 16); s2 += __shfl_xor(s2, o, 16); }
        mu = s * (1.f / 128.f);
        var = s2 * (1.f / 128.f) - mu * mu;
        rstd = rsqrtf(fmaxf(var, 0.f) + 1e-5f);
        union { ushort u[8]; uint4 v4; } oh, ol;
#pragma unroll
        for (int i = 0; i < 8; ++i) {
            int col = j * 8 + i;
            float o2 = (hv[i] - mu) * rstd * fn_g[col] + fn_b[col];
            ushort hh, ll; f2hl(o2, &hh, &ll);
            oh.u[i] = hh; ol.u[i] = ll;
        }
        *(uint4*)&hnH[(size_t)l * 128 + j * 8] = oh.v4;
        *(uint4*)&hnL[(size_t)l * 128 + j * 8] = ol.v4;
    }
}

// ---------------------------------------------------------------------------
// Win GEMM: 64x64 tiles, grid (128,8) = 1024 blocks. xp raw / sz silu split.
__global__ __launch_bounds__(256) void win_k(const ushort* __restrict__ Ah, const ushort* __restrict__ Al,
                                             const ushort* __restrict__ wH, const ushort* __restrict__ wL,
                                             const float* __restrict__ bin_,
                                             float* __restrict__ xp, float* __restrict__ sz) {
    __shared__ ushort AsH[64][72], AsL[64][72];
    __shared__ ushort BsH[64][72], BsL[64][72];
    const int tid = threadIdx.x;
    const int lane = tid & 63, wave = tid >> 6;
    const int wm = wave & 1, wn = wave >> 1;
    const int ln = lane & 15, q = lane >> 4;
    const int mb = blockIdx.x * 64, nb = blockIdx.y * 64;

    f32x4 acc[2][2];
#pragma unroll
    for (int rb = 0; rb < 2; ++rb)
#pragma unroll
        for (int cb = 0; cb < 2; ++cb) acc[rb][cb] = (f32x4){0.f, 0.f, 0.f, 0.f};

    for (int kc = 0; kc < 128; kc += 64) {
        __syncthreads();
        for (int u = tid; u < 512; u += 256) {
            int r = u >> 3, g = u & 7;
            size_t go = (size_t)(mb + r) * 128 + kc + g * 8;
            *(uint4*)&AsH[r][g * 8] = *(const uint4*)&Ah[go];
            *(uint4*)&AsL[r][g * 8] = *(const uint4*)&Al[go];
        }
        for (int u = tid; u < 512; u += 256) {
            int n = u >> 3, g = u & 7;
            size_t go = (size_t)(W_WIN) + (size_t)(nb + n) * 128 + kc + g * 8;
            *(uint4*)&BsH[n][g * 8] = *(const uint4*)&wH[go];
            *(uint4*)&BsL[n][g * 8] = *(const uint4*)&wL[go];
        }
        __syncthreads();
#pragma unroll
        for (int ks_ = 0; ks_ < 64; ks_ += 32) {
            const int kk = ks_ + q * 8;
            bf16x8 ah[2], al[2], bh[2], bl[2];
#pragma unroll
            for (int rb = 0; rb < 2; ++rb) {
                ah[rb] = *(const bf16x8*)&AsH[wm * 32 + rb * 16 + ln][kk];
                al[rb] = *(const bf16x8*)&AsL[wm * 32 + rb * 16 + ln][kk];
            }
#pragma unroll
            for (int cb = 0; cb < 2; ++cb) {
                bh[cb] = *(const bf16x8*)&BsH[wn * 32 + cb * 16 + ln][kk];
                bl[cb] = *(const bf16x8*)&BsL[wn * 32 + cb * 16 + ln][kk];
            }
#pragma unroll
            for (int rb = 0; rb < 2; ++rb)
#pragma unroll
                for (int cb = 0; cb < 2; ++cb) {
                    acc[rb][cb] = __builtin_amdgcn_mfma_f32_16x16x32_bf16(ah[rb], bh[cb], acc[rb][cb], 0, 0, 0);
                    acc[rb][cb] = __builtin_amdgcn_mfma_f32_16x16x32_bf16(ah[rb], bl[cb], acc[rb][cb], 0, 0, 0);
                    acc[rb][cb] = __builtin_amdgcn_mfma_f32_16x16x32_bf16(al[rb], bh[cb], acc[rb][cb], 0, 0, 0);
                }
        }
    }
#pragma unroll
    for (int rb = 0; rb < 2; ++rb)
#pragma unroll
        for (int cb = 0; cb < 2; ++cb)
#pragma unroll
            for (int r = 0; r < 4; ++r) {
                int l = mb + wm * 32 + rb * 16 + q * 4 + r;
                int col = nb + wn * 32 + cb * 16 + ln;
                float v = acc[rb][cb][r] + bin_[col];
                if (col < 256) {
                    xp[(size_t)l * 256 + col] = v;
                } else {
                    sz[(size_t)l * 256 + (col - 256)] = v * sigm(v);
                }
            }
}

// ---------------------------------------------------------------------------
// proj GEMM with conv+SiLU fused in front. 512 threads, grid 256 (32 rows each).
__global__ __launch_bounds__(512) void proj_k(const float* __restrict__ xp,
                                              const float* __restrict__ convw, const float* __restrict__ convb,
                                              const ushort* __restrict__ wH, const ushort* __restrict__ wL,
                                              const float* __restrict__ bdt, const float* __restrict__ mbuf,
                                              const float* __restrict__ edt, const float* __restrict__ eB,
                                              const float* __restrict__ eC, const float* __restrict__ wr,
                                              const float* __restrict__ wm,
                                              float* __restrict__ xc, float* __restrict__ dt,
                                              float* __restrict__ Bm, float* __restrict__ Cm) {
    __shared__ __align__(16) char smem[52224];
    ushort (*AsH)[264] = (ushort(*)[264])(smem);            // 32x264x2 = 16896
    ushort (*AsL)[264] = (ushort(*)[264])(smem + 16896);    // ..33792
    ushort (*BsH)[72]  = (ushort(*)[72])(smem + 33792);     // 64x72x2 = 9216
    ushort (*BsL)[72]  = (ushort(*)[72])(smem + 43008);     // ..52224
    const int tid = threadIdx.x;
    const int mb = blockIdx.x * 32;

    // ---- conv (4-tap causal) + SiLU, sliding window; -> xc global + LDS hi/lo
    {
        const int cg = tid & 63;       // col group: cols cg*4..+3
        const int rg = tid >> 6;       // row group: rows rg*4..+3
        const int c0 = cg * 4;
        float4 cb4 = *(const float4*)&convb[c0];
        float4 cw0 = *(const float4*)&convw[(c0 + 0) * 4];
        float4 cw1 = *(const float4*)&convw[(c0 + 1) * 4];
        float4 cw2 = *(const float4*)&convw[(c0 + 2) * 4];
        float4 cw3 = *(const float4*)&convw[(c0 + 3) * 4];
        const int lbase = mb + rg * 4;
        float4 zero = make_float4(0.f, 0.f, 0.f, 0.f);
        float4 x0 = (lbase - 3 >= 0) ? *(const float4*)&xp[(size_t)(lbase - 3) * 256 + c0] : zero;
        float4 x1 = (lbase - 2 >= 0) ? *(const float4*)&xp[(size_t)(lbase - 2) * 256 + c0] : zero;
        float4 x2 = (lbase - 1 >= 0) ? *(const float4*)&xp[(size_t)(lbase - 1) * 256 + c0] : zero;
#pragma unroll
        for (int rr = 0; rr < 4; ++rr) {
            int l = lbase + rr;
            float4 x3 = *(const float4*)&xp[(size_t)l * 256 + c0];
            float o0 = cb4.x + x0.x * cw0.x + x1.x * cw0.y + x2.x * cw0.z + x3.x * cw0.w;
            float o1 = cb4.y + x0.y * cw1.x + x1.y * cw1.y + x2.y * cw1.z + x3.y * cw1.w;
            float o2 = cb4.z + x0.z * cw2.x + x1.z * cw2.y + x2.z * cw2.z + x3.z * cw2.w;
            float o3 = cb4.w + x0.w * cw3.x + x1.w * cw3.y + x2.w * cw3.z + x3.w * cw3.w;
            o0 *= sigm(o0); o1 *= sigm(o1); o2 *= sigm(o2); o3 *= sigm(o3);
            *(float4*)&xc[(size_t)l * 256 + c0] = make_float4(o0, o1, o2, o3);
            union { ushort u[4]; uint2 v2; } hh, ll;
            f2hl(o0, &hh.u[0], &ll.u[0]); f2hl(o1, &hh.u[1], &ll.u[1]);
            f2hl(o2, &hh.u[2], &ll.u[2]); f2hl(o3, &hh.u[3], &ll.u[3]);
            int row = l - mb;
            *(uint2*)&AsH[row][c0] = hh.v2;
            *(uint2*)&AsL[row][c0] = ll.v2;
            x0 = x1; x1 = x2; x2 = x3;
        }
    }
    __syncthreads();

    // ---- GEMM 32x64 per iter, 5 iters, 8 waves
    const int lane = tid & 63, wave = tid >> 6;
    const int wm2 = wave & 1, wn4 = wave >> 1;
    const int ln = lane & 15, q = lane >> 4;
    for (int it = 0; it < 5; ++it) {
        int nb = it * 64;
        f32x4 acc = (f32x4){0.f, 0.f, 0.f, 0.f};
        for (int kc = 0; kc < 256; kc += 64) {
            __syncthreads();
            {
                int u = tid;   // 64 n-rows x 8 vec8 = 512
                int n = u >> 3, g = u & 7;
                size_t go = (size_t)(W_PROJ) + (size_t)(nb + n) * 256 + kc + g * 8;
                *(uint4*)&BsH[n][g * 8] = *(const uint4*)&wH[go];
                *(uint4*)&BsL[n][g * 8] = *(const uint4*)&wL[go];
            }
            __syncthreads();
#pragma unroll
            for (int ks_ = 0; ks_ < 64; ks_ += 32) {
                const int kka = kc + ks_ + q * 8;
                const int kkb = ks_ + q * 8;
                bf16x8 ah = *(const bf16x8*)&AsH[wm2 * 16 + ln][kka];
                bf16x8 al = *(const bf16x8*)&AsL[wm2 * 16 + ln][kka];
                bf16x8 bh = *(const bf16x8*)&BsH[wn4 * 16 + ln][kkb];
                bf16x8 bl = *(const bf16x8*)&BsL[wn4 * 16 + ln][kkb];
                acc = __builtin_amdgcn_mfma_f32_16x16x32_bf16(ah, bh, acc, 0, 0, 0);
                acc = __builtin_amdgcn_mfma_f32_16x16x32_bf16(ah, bl, acc, 0, 0, 0);
                acc = __builtin_amdgcn_mfma_f32_16x16x32_bf16(al, bh, acc, 0, 0, 0);
            }
        }
#pragma unroll
        for (int r = 0; r < 4; ++r) {
            int l = mb + wm2 * 16 + q * 4 + r;
            int col = nb + wn4 * 16 + ln;
            float v = acc[r];
            float rho = (float)l * (1.0f / 8191.0f);
            int band = min(7, (int)(rho * 8.0f));
            float mv = mbuf[l];
            if (col < 256) {
                float sc0 = 2.0f * sigm(edt[band] + wr[0] * rho + wm[0] * mv);
                float v2 = v + bdt[col];
                float sp = (v2 > 20.f) ? v2 : log1pf(expf(v2));
                dt[(size_t)l * 256 + col] = sp * sc0;
            } else if (col < 272) {
                float sc1 = 2.0f * sigm(eB[band] + wr[1] * rho + wm[1] * mv);
                Bm[(size_t)l * 16 + (col - 256)] = v * sc1;
            } else if (col < 288) {
                float sc2 = 2.0f * sigm(eC[band] + wr[2] * rho + wm[2] * mv);
                Cm[(size_t)l * 16 + (col - 272)] = v * sc2;
            }
        }
    }
}

// ---------------------------------------------------------------------------
// scan phase 0: chunk-local end states -> Hb, fwd chunk dt-sums -> sdtb
// CLh=16, grid (512,2) = 1024 blocks -> 4 blocks/CU (16 waves/CU).
__global__ __launch_bounds__(256, 4) void scan0_k(const float* __restrict__ dt, const float* __restrict__ xc,
                                                  const float* __restrict__ Bm, const float* __restrict__ Alog,
                                                  float* __restrict__ Hb, float* __restrict__ sdtb) {
    const int c = blockIdx.x, dir = blockIdx.y, e = threadIdx.x;
    __shared__ float bms[CLh][16];
    for (int idx = e; idx < CLh * 16; idx += 256)
        bms[idx >> 4][idx & 15] = Bm[c * (CLh * 16) + idx];
    float A2[16], iv[16], h[16];
#pragma unroll
    for (int n = 0; n < 16; ++n) {
        float ea = nexp2(Alog[e * 16 + n] * LOG2E);
        A2[n] = -ea * LOG2E;
        iv[n] = -1.0f / ea;
        h[n] = 0.f;
    }
    const int base = c * CLh;
    float cu[8], cx[8], nu[8], nx[8];
#pragma unroll
    for (int j = 0; j < 8; ++j) {
        int p = dir ? (CLh - 1 - j) : j;
        cu[j] = dt[(size_t)(base + p) * 256 + e];
        cx[j] = xc[(size_t)(base + p) * 256 + e];
    }
    __syncthreads();
    float sdt = 0.f;
#pragma unroll
    for (int g = 0; g < CLh / 8; ++g) {
        if (g + 1 < CLh / 8) {
#pragma unroll
            for (int j = 0; j < 8; ++j) {
                int s = (g + 1) * 8 + j;
                int p = dir ? (CLh - 1 - s) : s;
                nu[j] = dt[(size_t)(base + p) * 256 + e];
                nx[j] = xc[(size_t)(base + p) * 256 + e];
            }
        }
#pragma unroll
        for (int j = 0; j < 8; ++j) {
            int s = g * 8 + j;
            int p = dir ? (CLh - 1 - s) : s;
            float u = cu[j], xv = cx[j];
            union { float4 v[4]; float f[16]; } bb;
            const float4* bp = (const float4*)&bms[p][0];
            bb.v[0] = bp[0]; bb.v[1] = bp[1]; bb.v[2] = bp[2]; bb.v[3] = bp[3];
#pragma unroll
            for (int n = 0; n < 16; ++n) {
                float a = nexp2(A2[n] * u);
                float w = xv * bb.f[n] * iv[n];
                h[n] = a * (h[n] + w) - w;
            }
            sdt += u;
        }
#pragma unroll
        for (int j = 0; j < 8; ++j) { cu[j] = nu[j]; cx[j] = nx[j]; }
    }
    const size_t hofs = (size_t)(dir * NCh + c) * 4096 + e * 16;
#pragma unroll
    for (int j = 0; j < 4; ++j)
        *(float4*)&Hb[hofs + 4 * j] = make_float4(h[4 * j], h[4 * j + 1], h[4 * j + 2], h[4 * j + 3]);
    if (dir == 0) sdtb[c * 256 + e] = sdt;
}

// ---------------------------------------------------------------------------
// chunk combine, level 1: within-segment partial prefixes.
// 65536 threads = 8 seg x 2 dir x 4096 en; 64 serial steps each.
__global__ __launch_bounds__(256) void combine1_k(const float* __restrict__ Hb, const float* __restrict__ sdtb,
                                                  const float* __restrict__ Alog,
                                                  float* __restrict__ Hpp, float* __restrict__ cumsdtb,
                                                  float* __restrict__ segq, float* __restrict__ segsdt) {
    const int gid = blockIdx.x * 256 + threadIdx.x;   // < 65536
    const int seg = gid >> 13;                        // 0..7
    const int r = gid & 8191;
    const int d1 = r >> 12, en = r & 4095, e1 = en >> 4;
    const float A2e = -nexp2(Alog[en] * LOG2E) * LOG2E;
    float hi = 0.f, cum = 0.f;
    for (int k = 0; k < CPS; ++k) {
        const int pos = seg * CPS + k;
        const int c2 = d1 ? (NCh - 1 - pos) : pos;
        const size_t o2 = (size_t)(d1 * NCh + c2) * 4096 + en;
        const float sv = sdtb[c2 * 256 + e1];
        Hpp[o2] = hi;
        if ((en & 15) == 0) cumsdtb[(d1 * NCh + c2) * 256 + e1] = cum;
        hi = nexp2(A2e * sv) * hi + Hb[o2];
        cum += sv;
    }
    segq[(d1 * NSEG + seg) * 4096 + en] = hi;
    if ((en & 15) == 0) segsdt[(d1 * NSEG + seg) * 256 + e1] = cum;
}

// chunk combine, level 2: 8-step scan over segment summaries -> segpre.
__global__ __launch_bounds__(64) void combine2_k(const float* __restrict__ segq, const float* __restrict__ segsdt,
                                                 const float* __restrict__ Alog, float* __restrict__ segpre) {
    const int gid = blockIdx.x * 64 + threadIdx.x;    // < 8192
    const int d1 = gid >> 12, en = gid & 4095, e1 = en >> 4;
    const float A2e = -nexp2(Alog[en] * LOG2E) * LOG2E;
    float hi = 0.f;
#pragma unroll
    for (int s = 0; s < NSEG; ++s) {
        segpre[(d1 * NSEG + s) * 4096 + en] = hi;
        hi = nexp2(A2e * segsdt[(d1 * NSEG + s) * 256 + e1]) * hi + segq[(d1 * NSEG + s) * 4096 + en];
    }
}

// ---------------------------------------------------------------------------
// scan phase 1 + gate. Templated direction keeps yreg in VGPRs (no scratch).
template <int DIR>
static __device__ __forceinline__ void scan_dir(const float* __restrict__ dt, const float* __restrict__ xc,
                                                int base, int e,
                                                const float (*bms)[16], const float (*cms)[16],
                                                const float* A2, const float* iv,
                                                float* h, float* yreg) {
    float cu[8], cx[8], nu[8], nx[8];
#pragma unroll
    for (int j = 0; j < 8; ++j) {
        const int p = DIR ? (CLh - 1 - j) : j;
        cu[j] = dt[(size_t)(base + p) * 256 + e];
        cx[j] = xc[(size_t)(base + p) * 256 + e];
    }
#pragma unroll
    for (int g = 0; g < CLh / 8; ++g) {
        if (g + 1 < CLh / 8) {
#pragma unroll
            for (int j = 0; j < 8; ++j) {
                const int s = (g + 1) * 8 + j;
                const int p = DIR ? (CLh - 1 - s) : s;
                nu[j] = dt[(size_t)(base + p) * 256 + e];
                nx[j] = xc[(size_t)(base + p) * 256 + e];
            }
        }
#pragma unroll
        for (int j = 0; j < 8; ++j) {
            const int s = g * 8 + j;
            const int p = DIR ? (CLh - 1 - s) : s;
            float u = cu[j], xv = cx[j];
            union { float4 v[4]; float f[16]; } bb, cc;
            const float4* bp = (const float4*)&bms[p][0];
            bb.v[0] = bp[0]; bb.v[1] = bp[1]; bb.v[2] = bp[2]; bb.v[3] = bp[3];
            const float4* cp = (const float4*)&cms[p][0];
            cc.v[0] = cp[0]; cc.v[1] = cp[1]; cc.v[2] = cp[2]; cc.v[3] = cp[3];
            float y = 0.f;
#pragma unroll
            for (int n = 0; n < 16; ++n) {
                float a = nexp2(A2[n] * u);
                float w = xv * bb.f[n] * iv[n];
                h[n] = a * (h[n] + w) - w;
                y += h[n] * cc.f[n];
            }
            yreg[p] = y;
        }
#pragma unroll
        for (int j = 0; j < 8; ++j) { cu[j] = nu[j]; cx[j] = nx[j]; }
    }
}

// CLh=16, grid 512 blocks x 512 thr -> 2 blocks/CU (16 waves/CU).
__global__ __launch_bounds__(512, 4) void scan1g_k(const float* __restrict__ dt, const float* __restrict__ xc,
                                                   const float* __restrict__ Bm, const float* __restrict__ Cm,
                                                   const float* __restrict__ Alog,
                                                   const float* __restrict__ Hpp, const float* __restrict__ cumsdtb,
                                                   const float* __restrict__ segpre,
                                                   const float* __restrict__ sz, const float* __restrict__ Dp,
                                                   ushort* __restrict__ AHo, ushort* __restrict__ ALo) {
    const int c = blockIdx.x;
    const int tid = threadIdx.x;
    const int dir = tid >> 8;
    const int e = tid & 255;
    __shared__ float bms[CLh][16];
    __shared__ float cms[CLh][16];
    __shared__ float ysum[CLh][256];
    for (int idx = tid; idx < CLh * 16; idx += 512) {
        bms[idx >> 4][idx & 15] = Bm[c * (CLh * 16) + idx];
        cms[idx >> 4][idx & 15] = Cm[c * (CLh * 16) + idx];
    }
    float A2[16], iv[16], h[16];
#pragma unroll
    for (int n = 0; n < 16; ++n) {
        float ea = nexp2(Alog[e * 16 + n] * LOG2E);
        A2[n] = -ea * LOG2E;
        iv[n] = -1.0f / ea;
    }
    // entering state: hp = Hpp + exp2(A2*cum) * segpre
    {
        const int pos = dir ? (NCh - 1 - c) : c;
        const int seg = pos / CPS;
        const float cum = cumsdtb[(dir * NCh + c) * 256 + e];
        const size_t hofs = (size_t)(dir * NCh + c) * 4096 + e * 16;
        const size_t so = (size_t)(dir * NSEG + seg) * 4096 + e * 16;
#pragma unroll
        for (int jj = 0; jj < 4; ++jj) {
            float4 hv = *(const float4*)&Hpp[hofs + 4 * jj];
            float4 sv = *(const float4*)&segpre[so + 4 * jj];
            h[4 * jj + 0] = hv.x + nexp2(A2[4 * jj + 0] * cum) * sv.x;
            h[4 * jj + 1] = hv.y + nexp2(A2[4 * jj + 1] * cum) * sv.y;
            h[4 * jj + 2] = hv.z + nexp2(A2[4 * jj + 2] * cum) * sv.z;
            h[4 * jj + 3] = hv.w + nexp2(A2[4 * jj + 3] * cum) * sv.w;
        }
    }
    const int base = c * CLh;
    float yreg[CLh];
    __syncthreads();
    if (dir == 0) {
        scan_dir<0>(dt, xc, base, e, bms, cms, A2, iv, h, yreg);
    } else {
        scan_dir<1>(dt, xc, base, e, bms, cms, A2, iv, h, yreg);
    }
    __syncthreads();
    if (dir == 0) {
#pragma unroll
        for (int l = 0; l < CLh; ++l) ysum[l][e] = yreg[l];
    }
    __syncthreads();
    if (dir == 1) {
        float dpv = Dp[e];
#pragma unroll
        for (int l = 0; l < CLh; ++l) {
            size_t gl = (size_t)(base + l) * 256 + e;
            float a = (ysum[l][e] + yreg[l] + dpv * xc[gl]) * sz[gl];
            ushort hh, ll; f2hl(a, &hh, &ll);
            AHo[gl] = hh; ALo[gl] = ll;
        }
    }
}

// ---------------------------------------------------------------------------
// FUSED Wout + unembed. 32-row tile x full 128 cols, K=256 then K=128 through
// LDS (hf never touches global). Grid 256 x 512 threads (8 waves: 2 row x 4 col).
__global__ __launch_bounds__(512) void wu_k(const ushort* __restrict__ AH, const ushort* __restrict__ AL,
                                            const ushort* __restrict__ wH, const ushort* __restrict__ wL,
                                            const float* __restrict__ bout, const float* __restrict__ h_,
                                            const float* __restrict__ pu_b, const float* __restrict__ ks,
                                            float* __restrict__ out) {
    __shared__ __align__(16) char smem[70656];
    ushort (*AsH)[264] = (ushort(*)[264])(smem);            // 32x264x2 = 16896
    ushort (*AsL)[264] = (ushort(*)[264])(smem + 16896);    // ..33792
    ushort (*BsH)[72]  = (ushort(*)[72])(smem + 33792);     // 128x72x2 = 18432
    ushort (*BsL)[72]  = (ushort(*)[72])(smem + 52224);     // ..70656
    ushort (*hfH)[136] = (ushort(*)[136])(smem);            // overlay on As (As dead)
    ushort (*hfL)[136] = (ushort(*)[136])(smem + 8704);     // 32x136x2 = 8704 each

    const int tid = threadIdx.x;
    const int lane = tid & 63, wave = tid >> 6;
    const int wm = wave & 1, wn = wave >> 1;                // rows 2x16, cols 4x32
    const int ln = lane & 15, q = lane >> 4;
    const int mb = blockIdx.x * 32;

    // stage A (AHo/ALo) once for full K=256
    for (int u = tid; u < 1024; u += 512) {
        int r = u >> 5, g = u & 31;
        size_t go = (size_t)(mb + r) * 256 + g * 8;
        *(uint4*)&AsH[r][g * 8] = *(const uint4*)&AH[go];
        *(uint4*)&AsL[r][g * 8] = *(const uint4*)&AL[go];
    }

    f32x4 acc[2];
    acc[0] = (f32x4){0.f, 0.f, 0.f, 0.f};
    acc[1] = (f32x4){0.f, 0.f, 0.f, 0.f};

    // ---- Wout GEMM: hf[32][128] = A[32][256] @ Wout
    for (int kc = 0; kc < 256; kc += 64) {
        __syncthreads();
        for (int u = tid; u < 1024; u += 512) {
            int n = u >> 3, g = u & 7;
            size_t go = (size_t)(W_WOUT) + (size_t)n * 256 + kc + g * 8;
            *(uint4*)&BsH[n][g * 8] = *(const uint4*)&wH[go];
            *(uint4*)&BsL[n][g * 8] = *(const uint4*)&wL[go];
        }
        __syncthreads();
#pragma unroll
        for (int ks_ = 0; ks_ < 64; ks_ += 32) {
            const int kka = kc + ks_ + q * 8;
            const int kkb = ks_ + q * 8;
            bf16x8 ah = *(const bf16x8*)&AsH[wm * 16 + ln][kka];
            bf16x8 al = *(const bf16x8*)&AsL[wm * 16 + ln][kka];
#pragma unroll
            for (int cb = 0; cb < 2; ++cb) {
                bf16x8 bh = *(const bf16x8*)&BsH[wn * 32 + cb * 16 + ln][kkb];
                bf16x8 bl = *(const bf16x8*)&BsL[wn * 32 + cb * 16 + ln][kkb];
                acc[cb] = __builtin_amdgcn_mfma_f32_16x16x32_bf16(ah, bh, acc[cb], 0, 0, 0);
                acc[cb] = __builtin_amdgcn_mfma_f32_16x16x32_bf16(ah, bl, acc[cb], 0, 0, 0);
                acc[cb] = __builtin_amdgcn_mfma_f32_16x16x32_bf16(al, bh, acc[cb], 0, 0, 0);
            }
        }
    }
    __syncthreads();   // As reads done -> safe to overlay hf
    // epilogue 1: + bout + h_ residual -> hf in LDS (hi/lo)
#pragma unroll
    for (int cb = 0; cb < 2; ++cb)
#pragma unroll
        for (int r = 0; r < 4; ++r) {
            int row = wm * 16 + q * 4 + r;
            int col = wn * 32 + cb * 16 + ln;
            float v = acc[cb][r] + bout[col] + h_[(size_t)(mb + row) * 128 + col];
            ushort hh, ll; f2hl(v, &hh, &ll);
            hfH[row][col] = hh;
            hfL[row][col] = ll;
        }
    __syncthreads();

    // ---- unembed GEMM: out[32][128] = hf[32][128] @ pu^T (+pu_b +ks, scattered)
    f32x4 acc2[2];
    acc2[0] = (f32x4){0.f, 0.f, 0.f, 0.f};
    acc2[1] = (f32x4){0.f, 0.f, 0.f, 0.f};
    for (int kc = 0; kc < 128; kc += 64) {
        __syncthreads();
        for (int u = tid; u < 1024; u += 512) {
            int n = u >> 3, g = u & 7;
            size_t go = (size_t)(W_PU) + (size_t)n * 128 + kc + g * 8;
            *(uint4*)&BsH[n][g * 8] = *(const uint4*)&wH[go];
            *(uint4*)&BsL[n][g * 8] = *(const uint4*)&wL[go];
        }
        __syncthreads();
#pragma unroll
        for (int ks_ = 0; ks_ < 64; ks_ += 32) {
            const int kka = kc + ks_ + q * 8;
            const int kkb = ks_ + q * 8;
            bf16x8 ah = *(const bf16x8*)&hfH[wm * 16 + ln][kka];
            bf16x8 al = *(const bf16x8*)&hfL[wm * 16 + ln][kka];
#pragma unroll
            for (int cb = 0; cb < 2; ++cb) {
                bf16x8 bh = *(const bf16x8*)&BsH[wn * 32 + cb * 16 + ln][kkb];
                bf16x8 bl = *(const bf16x8*)&BsL[wn * 32 + cb * 16 + ln][kkb];
                acc2[cb] = __builtin_amdgcn_mfma_f32_16x16x32_bf16(ah, bh, acc2[cb], 0, 0, 0);
                acc2[cb] = __builtin_amdgcn_mfma_f32_16x16x32_bf16(ah, bl, acc2[cb], 0, 0, 0);
                acc2[cb] = __builtin_amdgcn_mfma_f32_16x16x32_bf16(al, bh, acc2[cb], 0, 0, 0);
            }
        }
    }
#pragma unroll
    for (int cb = 0; cb < 2; ++cb)
#pragma unroll
        for (int r = 0; r < 4; ++r) {
            int l = mb + wm * 16 + q * 4 + r;
            int col = wn * 32 + cb * 16 + ln;
            int xg = l >> 8, yg = (l >> 3) & 31, zg = l & 7;
            int cch = col >> 3, ijk = col & 7;
            int i2 = (ijk >> 2) & 1, j2 = (ijk >> 1) & 1, k2 = ijk & 1;
            size_t idx = (size_t)((cch * 64 + 2 * xg + i2) * 64 + (2 * yg + j2)) * 16 + 2 * zg + k2;
            out[idx] = acc2[cb][r] + pu_b[cch] + ks[idx];
        }
}

// ---------------------------------------------------------------------------
extern "C" void kernel_launch(void* const* d_in, const int* in_sizes, int n_in,
                              void* d_out, int out_size, void* d_ws, size_t ws_size,
                              hipStream_t stream) {
    const float* ks    = (const float*)d_in[0];
    const float* mask  = (const float*)d_in[1];
    const float* pe_w  = (const float*)d_in[2];
    const float* pe_b  = (const float*)d_in[3];
    const float* pu_w  = (const float*)d_in[4];
    const float* pu_b  = (const float*)d_in[5];
    const float* ln_g  = (const float*)d_in[6];
    const float* ln_b  = (const float*)d_in[7];
    const float* fn_g  = (const float*)d_in[8];
    const float* fn_b  = (const float*)d_in[9];
    const float* cond_band = (const float*)d_in[10];
    const float* cond_rad  = (const float*)d_in[11];
    const float* cond_mask = (const float*)d_in[12];
    const float* Win   = (const float*)d_in[13];
    const float* bin_  = (const float*)d_in[14];
    const float* convw = (const float*)d_in[15];
    const float* convb = (const float*)d_in[16];
    const float* Wx    = (const float*)d_in[17];
    const float* Wdt   = (const float*)d_in[18];
    const float* bdt   = (const float*)d_in[19];
    const float* Alog  = (const float*)d_in[20];
    const float* Dp    = (const float*)d_in[21];
    const float* Wout  = (const float*)d_in[22];
    const float* bout  = (const float*)d_in[23];
    const float* edt   = (const float*)d_in[24];
    const float* eB    = (const float*)d_in[25];
    const float* eC    = (const float*)d_in[26];
    const float* wr    = (const float*)d_in[27];
    const float* wm    = (const float*)d_in[28];
    float* out = (float*)d_out;

    char* base = (char*)d_ws;
    size_t o = 0;
    auto alloc = [&](size_t bytes) { char* p = base + o; o += (bytes + 255) & ~(size_t)255; return p; };
    float*  mbuf = (float*)alloc(32768);
    ushort* wH   = (ushort*)alloc(W_TOT * 2);
    ushort* wL   = (ushort*)alloc(W_TOT * 2);
    float*  h_   = (float*)alloc(4194304);
    ushort* hnH  = (ushort*)alloc(2097152);
    ushort* hnL  = (ushort*)alloc(2097152);
    float*  xp   = (float*)alloc(8388608);
    float*  sz   = (float*)alloc(8388608);
    float*  xc   = (float*)alloc(8388608);
    float*  dt   = (float*)alloc(8388608);
    float*  Bm   = (float*)alloc(524288);
    float*  Cm   = (float*)alloc(524288);
    float*  Hb   = (float*)alloc((size_t)2 * NCh * 4096 * 4);    // 16 MB
    float*  Hpp  = (float*)alloc((size_t)2 * NCh * 4096 * 4);    // 16 MB
    float*  sdtb = (float*)alloc((size_t)NCh * 256 * 4);         // 512 KB
    float*  cumsdtb = (float*)alloc((size_t)2 * NCh * 256 * 4);  // 1 MB
    float*  segq    = (float*)alloc((size_t)2 * NSEG * 4096 * 4);
    float*  segsdt  = (float*)alloc((size_t)2 * NSEG * 256 * 4);
    float*  segpre  = (float*)alloc((size_t)2 * NSEG * 4096 * 4);
    ushort* AHo  = (ushort*)alloc(4194304);
    ushort* ALo  = (ushort*)alloc(4194304);

    prep_k<<<864, 256, 0, stream>>>(pe_w, Win, Wx, Wdt, Wout, pu_w, mask, wH, wL, mbuf);
    embed_ln_k<<<512, 256, 0, stream>>>(ks, wH, wL, pe_b, cond_band, cond_rad, cond_mask, mbuf,
                                        ln_g, ln_b, fn_g, fn_b, h_, hnH, hnL);
    win_k<<<dim3(128, 8), 256, 0, stream>>>(hnH, hnL, wH, wL, bin_, xp, sz);
    proj_k<<<256, 512, 0, stream>>>(xp, convw, convb, wH, wL, bdt, mbuf, edt, eB, eC, wr, wm,
                                    xc, dt, Bm, Cm);
    scan0_k<<<dim3(NCh, 2), 256, 0, stream>>>(dt, xc, Bm, Alog, Hb, sdtb);
    combine1_k<<<256, 256, 0, stream>>>(Hb, sdtb, Alog, Hpp, cumsdtb, segq, segsdt);
    combine2_k<<<128, 64, 0, stream>>>(segq, segsdt, Alog, segpre);
    scan1g_k<<<NCh, 512, 0, stream>>>(dt, xc, Bm, Cm, Alog, Hpp, cumsdtb, segpre, sz, Dp, AHo, ALo);
    wu_k<<<256, 512, 0, stream>>>(AHo, ALo, wH, wL, bout, h_, pu_b, ks, out);
}

// Round 4
// 248.967 us; speedup vs baseline: 1.4857x; 1.4857x over previous
//
#include <hip/hip_runtime.h>
#include <hip/hip_bf16.h>

#define L_TOK 8192
#define NCh 512   // scan chunks
#define CLh 16    // chunk length
#define NSEG 8    // segments for chunk-combine
#define CPS (NCh / NSEG)   // chunks per segment = 64
#define LOG2E 1.44269504088896f

typedef short bf16x8 __attribute__((ext_vector_type(8)));
typedef float f32x4 __attribute__((ext_vector_type(4)));

static __device__ __forceinline__ float nexp2(float x) {
#if __has_builtin(__builtin_amdgcn_exp2f)
    return __builtin_amdgcn_exp2f(x);
#else
    return exp2f(x);
#endif
}
static __device__ __forceinline__ float sigm(float x) {
    return 1.f / (1.f + nexp2(-x * LOG2E));
}
static __device__ __forceinline__ ushort f2bf(float x) {
    union { float f; uint u; } v; v.f = x;
    uint r = v.u + 0x7fffu + ((v.u >> 16) & 1u);
    return (ushort)(r >> 16);
}
static __device__ __forceinline__ float bf2f(ushort h) {
    union { float f; uint u; } v; v.u = ((uint)h) << 16;
    return v.f;
}
static __device__ __forceinline__ void f2hl(float x, ushort* hi, ushort* lo) {
    ushort h = f2bf(x);
    *hi = h;
    *lo = f2bf(x - bf2f(h));
}

// weight regions in wH/wL (ushort elems), all K-major [n][k]:
#define W_PE   0
#define W_WIN  16384
#define W_WOUT 81920
#define W_PU   114688
#define W_PROJ 131072
#define W_TOT  212992

// ---------------------------------------------------------------------------
// prep: weights -> bf16 hi/lo (with transposes + Wx@Wdt fusion) ; maskpool
__global__ __launch_bounds__(256) void prep_k(const float* __restrict__ pe_w, const float* __restrict__ Win,
                                              const float* __restrict__ Wx, const float* __restrict__ Wdt,
                                              const float* __restrict__ Wout, const float* __restrict__ pu_w,
                                              const float* __restrict__ mask,
                                              ushort* __restrict__ wH, ushort* __restrict__ wL,
                                              float* __restrict__ mbuf) {
    int b = blockIdx.x;
    if (b >= 832) {  // maskpool
        int l = (b - 832) * 256 + threadIdx.x;
        int xg = l >> 8, yg = (l >> 3) & 31, zg = l & 7;
        float s = 0.f;
        for (int i2 = 0; i2 < 2; ++i2)
            for (int j2 = 0; j2 < 2; ++j2)
                for (int k2 = 0; k2 < 2; ++k2)
                    s += mask[(2 * xg + i2) * 1024 + (2 * yg + j2) * 16 + 2 * zg + k2];
        s *= 0.125f;
        mbuf[l] = fminf(fmaxf(s, 0.f), 1.f);
        return;
    }
    int i = b * 256 + threadIdx.x;  // < 212992
    float v;
    if (i < 16384) {
        v = pe_w[i];
    } else if (i < 81920) {
        int j = i - 16384; int n = j >> 7, k = j & 127;
        v = Win[k * 512 + n];
    } else if (i < 114688) {
        int j = i - 81920; int n = j >> 8, k = j & 255;
        v = Wout[k * 128 + n];
    } else if (i < 131072) {
        int j = i - 114688; int n = j >> 7, k = j & 127;
        v = pu_w[k * 128 + n];
    } else {
        int j = i - 131072; int n = j >> 8, k = j & 255;
        if (n < 256) {
            float s = 0.f;
#pragma unroll
            for (int r = 0; r < 8; ++r) s += Wx[k * 40 + r] * Wdt[r * 256 + n];
            v = s;
        } else if (n < 288) {
            v = Wx[k * 40 + 8 + (n - 256)];
        } else {
            v = 0.f;
        }
    }
    ushort h, lo; f2hl(v, &h, &lo);
    wH[i] = h; wL[i] = lo;
}

// ---------------------------------------------------------------------------
// fused: gather (LDS-staged, coalesced) -> embed GEMM (+pe_b+cond) -> LN2
// tile 16 x 128 (full N), 512 blocks, 256 threads.
__global__ __launch_bounds__(256) void embed_ln_k(const float* __restrict__ ks,
                                                  const ushort* __restrict__ wH, const ushort* __restrict__ wL,
                                                  const float* __restrict__ pe_b, const float* __restrict__ cond_band,
                                                  const float* __restrict__ cond_rad, const float* __restrict__ cond_mask,
                                                  const float* __restrict__ mbuf,
                                                  const float* __restrict__ ln_g, const float* __restrict__ ln_b,
                                                  const float* __restrict__ fn_g, const float* __restrict__ fn_b,
                                                  float* __restrict__ h_,
                                                  ushort* __restrict__ hnH, ushort* __restrict__ hnL) {
    __shared__ __align__(16) char smem[50176];
    ushort (*AsH)[72] = (ushort(*)[72])(smem);             // 16x72
    ushort (*AsL)[72] = (ushort(*)[72])(smem + 2304);
    ushort (*BsH)[72] = (ushort(*)[72])(smem + 4608);      // 128x72
    ushort (*BsL)[72] = (ushort(*)[72])(smem + 23040);     // ..41472
    float*  ksb       = (float*)(smem + 41472);            // 2176 floats (128 segs x 17)
    float  (*Cs)[132] = (float(*)[132])(smem);             // 16x132 (reuse after MFMA)

    const int tid = threadIdx.x;
    const int lane = tid & 63, wn = tid >> 6;
    const int ln = lane & 15, q = lane >> 4;
    const int mb = blockIdx.x * 16;
    const int xg = mb >> 8, yg0 = (mb >> 3) & 31;

    // coalesced stage of the block's kspace footprint:
    for (int v = tid; v < 512; v += 256) {
        int seg = v >> 2, zq = v & 3;
        int cc = seg >> 3, i2 = (seg >> 2) & 1, yy = seg & 3;
        float4 t4 = *(const float4*)&ks[cc * 65536 + (2 * xg + i2) * 1024 + (2 * yg0 + yy) * 16 + zq * 4];
        int la = seg * 17 + zq * 4;
        ksb[la] = t4.x; ksb[la + 1] = t4.y; ksb[la + 2] = t4.z; ksb[la + 3] = t4.w;
    }

    f32x4 acc[2];
    acc[0] = (f32x4){0.f, 0.f, 0.f, 0.f};
    acc[1] = (f32x4){0.f, 0.f, 0.f, 0.f};

    for (int kc = 0; kc < 128; kc += 64) {
        __syncthreads();
        for (int u = tid; u < 1024; u += 256) {
            int r = u >> 6, kk = u & 63;
            int k = kc + kk;
            int cc = k >> 3, ijk = k & 7;
            int i2 = (ijk >> 2) & 1, j2 = (ijk >> 1) & 1, k2 = ijk & 1;
            int seg = (cc * 2 + i2) * 4 + (r >> 3) * 2 + j2;
            float v = ksb[seg * 17 + (r & 7) * 2 + k2];
            ushort hh, ll; f2hl(v, &hh, &ll);
            AsH[r][kk] = hh; AsL[r][kk] = ll;
        }
        for (int u = tid; u < 1024; u += 256) {
            int n = u >> 3, g = u & 7;
            *(uint4*)&BsH[n][g * 8] = *(const uint4*)&wH[W_PE + n * 128 + kc + g * 8];
            *(uint4*)&BsL[n][g * 8] = *(const uint4*)&wL[W_PE + n * 128 + kc + g * 8];
        }
        __syncthreads();
#pragma unroll
        for (int ks_ = 0; ks_ < 64; ks_ += 32) {
            const int kk = ks_ + q * 8;
            bf16x8 ah = *(const bf16x8*)&AsH[ln][kk];
            bf16x8 al = *(const bf16x8*)&AsL[ln][kk];
#pragma unroll
            for (int cb = 0; cb < 2; ++cb) {
                bf16x8 bh = *(const bf16x8*)&BsH[wn * 32 + cb * 16 + ln][kk];
                bf16x8 bl = *(const bf16x8*)&BsL[wn * 32 + cb * 16 + ln][kk];
                acc[cb] = __builtin_amdgcn_mfma_f32_16x16x32_bf16(ah, bh, acc[cb], 0, 0, 0);
                acc[cb] = __builtin_amdgcn_mfma_f32_16x16x32_bf16(ah, bl, acc[cb], 0, 0, 0);
                acc[cb] = __builtin_amdgcn_mfma_f32_16x16x32_bf16(al, bh, acc[cb], 0, 0, 0);
            }
        }
    }
    __syncthreads();
#pragma unroll
    for (int cb = 0; cb < 2; ++cb) {
#pragma unroll
        for (int r = 0; r < 4; ++r) {
            int row = q * 4 + r;
            int col = wn * 32 + cb * 16 + ln;
            int l = mb + row;
            float rho = (float)l * (1.0f / 8191.0f);
            int band = min(7, (int)(rho * 8.0f));
            Cs[row][col] = acc[cb][r] + pe_b[col] + cond_band[band * 128 + col]
                           + rho * cond_rad[col] + mbuf[l] * cond_mask[col];
        }
    }
    __syncthreads();
    {
        int row = tid >> 4, j = tid & 15;
        int l = mb + row;
        float v8[8];
        float s = 0.f, s2 = 0.f;
#pragma unroll
        for (int i = 0; i < 8; ++i) {
            float v = Cs[row][j * 8 + i];
            v8[i] = v; s += v; s2 += v * v;
        }
#pragma unroll
        for (int o = 1; o < 16; o <<= 1) { s += __shfl_xor(s, o, 16); s2 += __shfl_xor(s2, o, 16); }
        float mu = s * (1.f / 128.f);
        float var = s2 * (1.f / 128.f) - mu * mu;
        float rstd = rsqrtf(fmaxf(var, 0.f) + 1e-5f);
        float hv[8];
        s = 0.f; s2 = 0.f;
#pragma unroll
        for (int i = 0; i < 8; ++i) {
            int col = j * 8 + i;
            float h = (v8[i] - mu) * rstd * ln_g[col] + ln_b[col];
            hv[i] = h; s += h; s2 += h * h;
        }
#pragma unroll
        for (int i = 0; i < 8; i += 4)
            *(float4*)&h_[(size_t)l * 128 + j * 8 + i] = make_float4(hv[i], hv[i + 1], hv[i + 2], hv[i + 3]);
#pragma unroll
        for (int o = 1; o < 16; o <<= 1) { s += __shfl_xor(s, o, 16); s2 += __shfl_xor(s2, o, 16); }
        mu = s * (1.f / 128.f);
        var = s2 * (1.f / 128.f) - mu * mu;
        rstd = rsqrtf(fmaxf(var, 0.f) + 1e-5f);
        union { ushort u[8]; uint4 v4; } oh, ol;
#pragma unroll
        for (int i = 0; i < 8; ++i) {
            int col = j * 8 + i;
            float o2 = (hv[i] - mu) * rstd * fn_g[col] + fn_b[col];
            ushort hh, ll; f2hl(o2, &hh, &ll);
            oh.u[i] = hh; ol.u[i] = ll;
        }
        *(uint4*)&hnH[(size_t)l * 128 + j * 8] = oh.v4;
        *(uint4*)&hnL[(size_t)l * 128 + j * 8] = ol.v4;
    }
}

// ---------------------------------------------------------------------------
// Win GEMM: 64x64 tiles, grid (128,8) = 1024 blocks. xp raw / sz silu split.
__global__ __launch_bounds__(256) void win_k(const ushort* __restrict__ Ah, const ushort* __restrict__ Al,
                                             const ushort* __restrict__ wH, const ushort* __restrict__ wL,
                                             const float* __restrict__ bin_,
                                             float* __restrict__ xp, float* __restrict__ sz) {
    __shared__ ushort AsH[64][72], AsL[64][72];
    __shared__ ushort BsH[64][72], BsL[64][72];
    const int tid = threadIdx.x;
    const int lane = tid & 63, wave = tid >> 6;
    const int wm = wave & 1, wn = wave >> 1;
    const int ln = lane & 15, q = lane >> 4;
    const int mb = blockIdx.x * 64, nb = blockIdx.y * 64;

    f32x4 acc[2][2];
#pragma unroll
    for (int rb = 0; rb < 2; ++rb)
#pragma unroll
        for (int cb = 0; cb < 2; ++cb) acc[rb][cb] = (f32x4){0.f, 0.f, 0.f, 0.f};

    for (int kc = 0; kc < 128; kc += 64) {
        __syncthreads();
        for (int u = tid; u < 512; u += 256) {
            int r = u >> 3, g = u & 7;
            size_t go = (size_t)(mb + r) * 128 + kc + g * 8;
            *(uint4*)&AsH[r][g * 8] = *(const uint4*)&Ah[go];
            *(uint4*)&AsL[r][g * 8] = *(const uint4*)&Al[go];
        }
        for (int u = tid; u < 512; u += 256) {
            int n = u >> 3, g = u & 7;
            size_t go = (size_t)(W_WIN) + (size_t)(nb + n) * 128 + kc + g * 8;
            *(uint4*)&BsH[n][g * 8] = *(const uint4*)&wH[go];
            *(uint4*)&BsL[n][g * 8] = *(const uint4*)&wL[go];
        }
        __syncthreads();
#pragma unroll
        for (int ks_ = 0; ks_ < 64; ks_ += 32) {
            const int kk = ks_ + q * 8;
            bf16x8 ah[2], al[2], bh[2], bl[2];
#pragma unroll
            for (int rb = 0; rb < 2; ++rb) {
                ah[rb] = *(const bf16x8*)&AsH[wm * 32 + rb * 16 + ln][kk];
                al[rb] = *(const bf16x8*)&AsL[wm * 32 + rb * 16 + ln][kk];
            }
#pragma unroll
            for (int cb = 0; cb < 2; ++cb) {
                bh[cb] = *(const bf16x8*)&BsH[wn * 32 + cb * 16 + ln][kk];
                bl[cb] = *(const bf16x8*)&BsL[wn * 32 + cb * 16 + ln][kk];
            }
#pragma unroll
            for (int rb = 0; rb < 2; ++rb)
#pragma unroll
                for (int cb = 0; cb < 2; ++cb) {
                    acc[rb][cb] = __builtin_amdgcn_mfma_f32_16x16x32_bf16(ah[rb], bh[cb], acc[rb][cb], 0, 0, 0);
                    acc[rb][cb] = __builtin_amdgcn_mfma_f32_16x16x32_bf16(ah[rb], bl[cb], acc[rb][cb], 0, 0, 0);
                    acc[rb][cb] = __builtin_amdgcn_mfma_f32_16x16x32_bf16(al[rb], bh[cb], acc[rb][cb], 0, 0, 0);
                }
        }
    }
#pragma unroll
    for (int rb = 0; rb < 2; ++rb)
#pragma unroll
        for (int cb = 0; cb < 2; ++cb)
#pragma unroll
            for (int r = 0; r < 4; ++r) {
                int l = mb + wm * 32 + rb * 16 + q * 4 + r;
                int col = nb + wn * 32 + cb * 16 + ln;
                float v = acc[rb][cb][r] + bin_[col];
                if (col < 256) {
                    xp[(size_t)l * 256 + col] = v;
                } else {
                    sz[(size_t)l * 256 + (col - 256)] = v * sigm(v);
                }
            }
}

// ---------------------------------------------------------------------------
// proj GEMM with conv+SiLU fused in front. 512 threads, grid 256 (32 rows each).
__global__ __launch_bounds__(512) void proj_k(const float* __restrict__ xp,
                                              const float* __restrict__ convw, const float* __restrict__ convb,
                                              const ushort* __restrict__ wH, const ushort* __restrict__ wL,
                                              const float* __restrict__ bdt, const float* __restrict__ mbuf,
                                              const float* __restrict__ edt, const float* __restrict__ eB,
                                              const float* __restrict__ eC, const float* __restrict__ wr,
                                              const float* __restrict__ wm,
                                              float* __restrict__ xc, float* __restrict__ dt,
                                              float* __restrict__ Bm, float* __restrict__ Cm) {
    __shared__ __align__(16) char smem[52224];
    ushort (*AsH)[264] = (ushort(*)[264])(smem);            // 32x264x2 = 16896
    ushort (*AsL)[264] = (ushort(*)[264])(smem + 16896);    // ..33792
    ushort (*BsH)[72]  = (ushort(*)[72])(smem + 33792);     // 64x72x2 = 9216
    ushort (*BsL)[72]  = (ushort(*)[72])(smem + 43008);     // ..52224
    const int tid = threadIdx.x;
    const int mb = blockIdx.x * 32;

    // ---- conv (4-tap causal) + SiLU, sliding window; -> xc global + LDS hi/lo
    {
        const int cg = tid & 63;       // col group: cols cg*4..+3
        const int rg = tid >> 6;       // row group: rows rg*4..+3
        const int c0 = cg * 4;
        float4 cb4 = *(const float4*)&convb[c0];
        float4 cw0 = *(const float4*)&convw[(c0 + 0) * 4];
        float4 cw1 = *(const float4*)&convw[(c0 + 1) * 4];
        float4 cw2 = *(const float4*)&convw[(c0 + 2) * 4];
        float4 cw3 = *(const float4*)&convw[(c0 + 3) * 4];
        const int lbase = mb + rg * 4;
        float4 zero = make_float4(0.f, 0.f, 0.f, 0.f);
        float4 x0 = (lbase - 3 >= 0) ? *(const float4*)&xp[(size_t)(lbase - 3) * 256 + c0] : zero;
        float4 x1 = (lbase - 2 >= 0) ? *(const float4*)&xp[(size_t)(lbase - 2) * 256 + c0] : zero;
        float4 x2 = (lbase - 1 >= 0) ? *(const float4*)&xp[(size_t)(lbase - 1) * 256 + c0] : zero;
#pragma unroll
        for (int rr = 0; rr < 4; ++rr) {
            int l = lbase + rr;
            float4 x3 = *(const float4*)&xp[(size_t)l * 256 + c0];
            float o0 = cb4.x + x0.x * cw0.x + x1.x * cw0.y + x2.x * cw0.z + x3.x * cw0.w;
            float o1 = cb4.y + x0.y * cw1.x + x1.y * cw1.y + x2.y * cw1.z + x3.y * cw1.w;
            float o2 = cb4.z + x0.z * cw2.x + x1.z * cw2.y + x2.z * cw2.z + x3.z * cw2.w;
            float o3 = cb4.w + x0.w * cw3.x + x1.w * cw3.y + x2.w * cw3.z + x3.w * cw3.w;
            o0 *= sigm(o0); o1 *= sigm(o1); o2 *= sigm(o2); o3 *= sigm(o3);
            *(float4*)&xc[(size_t)l * 256 + c0] = make_float4(o0, o1, o2, o3);
            union { ushort u[4]; uint2 v2; } hh, ll;
            f2hl(o0, &hh.u[0], &ll.u[0]); f2hl(o1, &hh.u[1], &ll.u[1]);
            f2hl(o2, &hh.u[2], &ll.u[2]); f2hl(o3, &hh.u[3], &ll.u[3]);
            int row = l - mb;
            *(uint2*)&AsH[row][c0] = hh.v2;
            *(uint2*)&AsL[row][c0] = ll.v2;
            x0 = x1; x1 = x2; x2 = x3;
        }
    }
    __syncthreads();

    // ---- GEMM 32x64 per iter, 5 iters, 8 waves
    const int lane = tid & 63, wave = tid >> 6;
    const int wm2 = wave & 1, wn4 = wave >> 1;
    const int ln = lane & 15, q = lane >> 4;
    for (int it = 0; it < 5; ++it) {
        int nb = it * 64;
        f32x4 acc = (f32x4){0.f, 0.f, 0.f, 0.f};
        for (int kc = 0; kc < 256; kc += 64) {
            __syncthreads();
            {
                int u = tid;   // 64 n-rows x 8 vec8 = 512
                int n = u >> 3, g = u & 7;
                size_t go = (size_t)(W_PROJ) + (size_t)(nb + n) * 256 + kc + g * 8;
                *(uint4*)&BsH[n][g * 8] = *(const uint4*)&wH[go];
                *(uint4*)&BsL[n][g * 8] = *(const uint4*)&wL[go];
            }
            __syncthreads();
#pragma unroll
            for (int ks_ = 0; ks_ < 64; ks_ += 32) {
                const int kka = kc + ks_ + q * 8;
                const int kkb = ks_ + q * 8;
                bf16x8 ah = *(const bf16x8*)&AsH[wm2 * 16 + ln][kka];
                bf16x8 al = *(const bf16x8*)&AsL[wm2 * 16 + ln][kka];
                bf16x8 bh = *(const bf16x8*)&BsH[wn4 * 16 + ln][kkb];
                bf16x8 bl = *(const bf16x8*)&BsL[wn4 * 16 + ln][kkb];
                acc = __builtin_amdgcn_mfma_f32_16x16x32_bf16(ah, bh, acc, 0, 0, 0);
                acc = __builtin_amdgcn_mfma_f32_16x16x32_bf16(ah, bl, acc, 0, 0, 0);
                acc = __builtin_amdgcn_mfma_f32_16x16x32_bf16(al, bh, acc, 0, 0, 0);
            }
        }
#pragma unroll
        for (int r = 0; r < 4; ++r) {
            int l = mb + wm2 * 16 + q * 4 + r;
            int col = nb + wn4 * 16 + ln;
            float v = acc[r];
            float rho = (float)l * (1.0f / 8191.0f);
            int band = min(7, (int)(rho * 8.0f));
            float mv = mbuf[l];
            if (col < 256) {
                float sc0 = 2.0f * sigm(edt[band] + wr[0] * rho + wm[0] * mv);
                float v2 = v + bdt[col];
                float sp = (v2 > 20.f) ? v2 : log1pf(expf(v2));
                dt[(size_t)l * 256 + col] = sp * sc0;
            } else if (col < 272) {
                float sc1 = 2.0f * sigm(eB[band] + wr[1] * rho + wm[1] * mv);
                Bm[(size_t)l * 16 + (col - 256)] = v * sc1;
            } else if (col < 288) {
                float sc2 = 2.0f * sigm(eC[band] + wr[2] * rho + wm[2] * mv);
                Cm[(size_t)l * 16 + (col - 272)] = v * sc2;
            }
        }
    }
}

// ---------------------------------------------------------------------------
// scan phase 0: chunk-local end states -> Hb, fwd chunk dt-sums -> sdtb
// CLh=16, grid (512,2) = 1024 blocks -> 4 blocks/CU (16 waves/CU).
__global__ __launch_bounds__(256, 4) void scan0_k(const float* __restrict__ dt, const float* __restrict__ xc,
                                                  const float* __restrict__ Bm, const float* __restrict__ Alog,
                                                  float* __restrict__ Hb, float* __restrict__ sdtb) {
    const int c = blockIdx.x, dir = blockIdx.y, e = threadIdx.x;
    __shared__ float bms[CLh][16];
    for (int idx = e; idx < CLh * 16; idx += 256)
        bms[idx >> 4][idx & 15] = Bm[c * (CLh * 16) + idx];
    float A2[16], iv[16], h[16];
#pragma unroll
    for (int n = 0; n < 16; ++n) {
        float ea = nexp2(Alog[e * 16 + n] * LOG2E);
        A2[n] = -ea * LOG2E;
        iv[n] = -1.0f / ea;
        h[n] = 0.f;
    }
    const int base = c * CLh;
    float cu[8], cx[8], nu[8], nx[8];
#pragma unroll
    for (int j = 0; j < 8; ++j) {
        int p = dir ? (CLh - 1 - j) : j;
        cu[j] = dt[(size_t)(base + p) * 256 + e];
        cx[j] = xc[(size_t)(base + p) * 256 + e];
    }
    __syncthreads();
    float sdt = 0.f;
#pragma unroll
    for (int g = 0; g < CLh / 8; ++g) {
        if (g + 1 < CLh / 8) {
#pragma unroll
            for (int j = 0; j < 8; ++j) {
                int s = (g + 1) * 8 + j;
                int p = dir ? (CLh - 1 - s) : s;
                nu[j] = dt[(size_t)(base + p) * 256 + e];
                nx[j] = xc[(size_t)(base + p) * 256 + e];
            }
        }
#pragma unroll
        for (int j = 0; j < 8; ++j) {
            int s = g * 8 + j;
            int p = dir ? (CLh - 1 - s) : s;
            float u = cu[j], xv = cx[j];
            union { float4 v[4]; float f[16]; } bb;
            const float4* bp = (const float4*)&bms[p][0];
            bb.v[0] = bp[0]; bb.v[1] = bp[1]; bb.v[2] = bp[2]; bb.v[3] = bp[3];
#pragma unroll
            for (int n = 0; n < 16; ++n) {
                float a = nexp2(A2[n] * u);
                float w = xv * bb.f[n] * iv[n];
                h[n] = a * (h[n] + w) - w;
            }
            sdt += u;
        }
#pragma unroll
        for (int j = 0; j < 8; ++j) { cu[j] = nu[j]; cx[j] = nx[j]; }
    }
    const size_t hofs = (size_t)(dir * NCh + c) * 4096 + e * 16;
#pragma unroll
    for (int j = 0; j < 4; ++j)
        *(float4*)&Hb[hofs + 4 * j] = make_float4(h[4 * j], h[4 * j + 1], h[4 * j + 2], h[4 * j + 3]);
    if (dir == 0) sdtb[c * 256 + e] = sdt;
}

// ---------------------------------------------------------------------------
// chunk combine, level 1: within-segment partial prefixes.
// 65536 threads = 8 seg x 2 dir x 4096 en; 64 serial steps each.
__global__ __launch_bounds__(256) void combine1_k(const float* __restrict__ Hb, const float* __restrict__ sdtb,
                                                  const float* __restrict__ Alog,
                                                  float* __restrict__ Hpp, float* __restrict__ cumsdtb,
                                                  float* __restrict__ segq, float* __restrict__ segsdt) {
    const int gid = blockIdx.x * 256 + threadIdx.x;   // < 65536
    const int seg = gid >> 13;                        // 0..7
    const int r = gid & 8191;
    const int d1 = r >> 12, en = r & 4095, e1 = en >> 4;
    const float A2e = -nexp2(Alog[en] * LOG2E) * LOG2E;
    float hi = 0.f, cum = 0.f;
    for (int k = 0; k < CPS; ++k) {
        const int pos = seg * CPS + k;
        const int c2 = d1 ? (NCh - 1 - pos) : pos;
        const size_t o2 = (size_t)(d1 * NCh + c2) * 4096 + en;
        const float sv = sdtb[c2 * 256 + e1];
        Hpp[o2] = hi;
        if ((en & 15) == 0) cumsdtb[(d1 * NCh + c2) * 256 + e1] = cum;
        hi = nexp2(A2e * sv) * hi + Hb[o2];
        cum += sv;
    }
    segq[(d1 * NSEG + seg) * 4096 + en] = hi;
    if ((en & 15) == 0) segsdt[(d1 * NSEG + seg) * 256 + e1] = cum;
}

// chunk combine, level 2: 8-step scan over segment summaries -> segpre.
__global__ __launch_bounds__(64) void combine2_k(const float* __restrict__ segq, const float* __restrict__ segsdt,
                                                 const float* __restrict__ Alog, float* __restrict__ segpre) {
    const int gid = blockIdx.x * 64 + threadIdx.x;    // < 8192
    const int d1 = gid >> 12, en = gid & 4095, e1 = en >> 4;
    const float A2e = -nexp2(Alog[en] * LOG2E) * LOG2E;
    float hi = 0.f;
#pragma unroll
    for (int s = 0; s < NSEG; ++s) {
        segpre[(d1 * NSEG + s) * 4096 + en] = hi;
        hi = nexp2(A2e * segsdt[(d1 * NSEG + s) * 256 + e1]) * hi + segq[(d1 * NSEG + s) * 4096 + en];
    }
}

// ---------------------------------------------------------------------------
// scan phase 1 + gate. Templated direction keeps yreg in VGPRs (no scratch).
template <int DIR>
static __device__ __forceinline__ void scan_dir(const float* __restrict__ dt, const float* __restrict__ xc,
                                                int base, int e,
                                                const float (*bms)[16], const float (*cms)[16],
                                                const float* A2, const float* iv,
                                                float* h, float* yreg) {
    float cu[8], cx[8], nu[8], nx[8];
#pragma unroll
    for (int j = 0; j < 8; ++j) {
        const int p = DIR ? (CLh - 1 - j) : j;
        cu[j] = dt[(size_t)(base + p) * 256 + e];
        cx[j] = xc[(size_t)(base + p) * 256 + e];
    }
#pragma unroll
    for (int g = 0; g < CLh / 8; ++g) {
        if (g + 1 < CLh / 8) {
#pragma unroll
            for (int j = 0; j < 8; ++j) {
                const int s = (g + 1) * 8 + j;
                const int p = DIR ? (CLh - 1 - s) : s;
                nu[j] = dt[(size_t)(base + p) * 256 + e];
                nx[j] = xc[(size_t)(base + p) * 256 + e];
            }
        }
#pragma unroll
        for (int j = 0; j < 8; ++j) {
            const int s = g * 8 + j;
            const int p = DIR ? (CLh - 1 - s) : s;
            float u = cu[j], xv = cx[j];
            union { float4 v[4]; float f[16]; } bb, cc;
            const float4* bp = (const float4*)&bms[p][0];
            bb.v[0] = bp[0]; bb.v[1] = bp[1]; bb.v[2] = bp[2]; bb.v[3] = bp[3];
            const float4* cp = (const float4*)&cms[p][0];
            cc.v[0] = cp[0]; cc.v[1] = cp[1]; cc.v[2] = cp[2]; cc.v[3] = cp[3];
            float y = 0.f;
#pragma unroll
            for (int n = 0; n < 16; ++n) {
                float a = nexp2(A2[n] * u);
                float w = xv * bb.f[n] * iv[n];
                h[n] = a * (h[n] + w) - w;
                y += h[n] * cc.f[n];
            }
            yreg[p] = y;
        }
#pragma unroll
        for (int j = 0; j < 8; ++j) { cu[j] = nu[j]; cx[j] = nx[j]; }
    }
}

// CLh=16, grid 512 blocks x 512 thr. NO min-occupancy bound: (512,4) forced a
// 64-VGPR cap -> scratch spills (round 3: WRITE_SIZE 353 MB, 154 us). Default
// allocation (~124 VGPR, round 2) has zero spill.
__global__ __launch_bounds__(512) void scan1g_k(const float* __restrict__ dt, const float* __restrict__ xc,
                                                const float* __restrict__ Bm, const float* __restrict__ Cm,
                                                const float* __restrict__ Alog,
                                                const float* __restrict__ Hpp, const float* __restrict__ cumsdtb,
                                                const float* __restrict__ segpre,
                                                const float* __restrict__ sz, const float* __restrict__ Dp,
                                                ushort* __restrict__ AHo, ushort* __restrict__ ALo) {
    const int c = blockIdx.x;
    const int tid = threadIdx.x;
    const int dir = tid >> 8;
    const int e = tid & 255;
    __shared__ float bms[CLh][16];
    __shared__ float cms[CLh][16];
    __shared__ float ysum[CLh][256];
    for (int idx = tid; idx < CLh * 16; idx += 512) {
        bms[idx >> 4][idx & 15] = Bm[c * (CLh * 16) + idx];
        cms[idx >> 4][idx & 15] = Cm[c * (CLh * 16) + idx];
    }
    float A2[16], iv[16], h[16];
#pragma unroll
    for (int n = 0; n < 16; ++n) {
        float ea = nexp2(Alog[e * 16 + n] * LOG2E);
        A2[n] = -ea * LOG2E;
        iv[n] = -1.0f / ea;
    }
    // entering state: hp = Hpp + exp2(A2*cum) * segpre
    {
        const int pos = dir ? (NCh - 1 - c) : c;
        const int seg = pos / CPS;
        const float cum = cumsdtb[(dir * NCh + c) * 256 + e];
        const size_t hofs = (size_t)(dir * NCh + c) * 4096 + e * 16;
        const size_t so = (size_t)(dir * NSEG + seg) * 4096 + e * 16;
#pragma unroll
        for (int jj = 0; jj < 4; ++jj) {
            float4 hv = *(const float4*)&Hpp[hofs + 4 * jj];
            float4 sv = *(const float4*)&segpre[so + 4 * jj];
            h[4 * jj + 0] = hv.x + nexp2(A2[4 * jj + 0] * cum) * sv.x;
            h[4 * jj + 1] = hv.y + nexp2(A2[4 * jj + 1] * cum) * sv.y;
            h[4 * jj + 2] = hv.z + nexp2(A2[4 * jj + 2] * cum) * sv.z;
            h[4 * jj + 3] = hv.w + nexp2(A2[4 * jj + 3] * cum) * sv.w;
        }
    }
    const int base = c * CLh;
    float yreg[CLh];
    __syncthreads();
    if (dir == 0) {
        scan_dir<0>(dt, xc, base, e, bms, cms, A2, iv, h, yreg);
    } else {
        scan_dir<1>(dt, xc, base, e, bms, cms, A2, iv, h, yreg);
    }
    __syncthreads();
    if (dir == 0) {
#pragma unroll
        for (int l = 0; l < CLh; ++l) ysum[l][e] = yreg[l];
    }
    __syncthreads();
    if (dir == 1) {
        float dpv = Dp[e];
#pragma unroll
        for (int l = 0; l < CLh; ++l) {
            size_t gl = (size_t)(base + l) * 256 + e;
            float a = (ysum[l][e] + yreg[l] + dpv * xc[gl]) * sz[gl];
            ushort hh, ll; f2hl(a, &hh, &ll);
            AHo[gl] = hh; ALo[gl] = ll;
        }
    }
}

// ---------------------------------------------------------------------------
// FUSED Wout + unembed. 32-row tile x full 128 cols, K=256 then K=128 through
// LDS (hf never touches global). Grid 256 x 512 threads (8 waves: 2 row x 4 col).
__global__ __launch_bounds__(512) void wu_k(const ushort* __restrict__ AH, const ushort* __restrict__ AL,
                                            const ushort* __restrict__ wH, const ushort* __restrict__ wL,
                                            const float* __restrict__ bout, const float* __restrict__ h_,
                                            const float* __restrict__ pu_b, const float* __restrict__ ks,
                                            float* __restrict__ out) {
    __shared__ __align__(16) char smem[70656];
    ushort (*AsH)[264] = (ushort(*)[264])(smem);            // 32x264x2 = 16896
    ushort (*AsL)[264] = (ushort(*)[264])(smem + 16896);    // ..33792
    ushort (*BsH)[72]  = (ushort(*)[72])(smem + 33792);     // 128x72x2 = 18432
    ushort (*BsL)[72]  = (ushort(*)[72])(smem + 52224);     // ..70656
    ushort (*hfH)[136] = (ushort(*)[136])(smem);            // overlay on As (As dead)
    ushort (*hfL)[136] = (ushort(*)[136])(smem + 8704);     // 32x136x2 = 8704 each

    const int tid = threadIdx.x;
    const int lane = tid & 63, wave = tid >> 6;
    const int wm = wave & 1, wn = wave >> 1;                // rows 2x16, cols 4x32
    const int ln = lane & 15, q = lane >> 4;
    const int mb = blockIdx.x * 32;

    // stage A (AHo/ALo) once for full K=256
    for (int u = tid; u < 1024; u += 512) {
        int r = u >> 5, g = u & 31;
        size_t go = (size_t)(mb + r) * 256 + g * 8;
        *(uint4*)&AsH[r][g * 8] = *(const uint4*)&AH[go];
        *(uint4*)&AsL[r][g * 8] = *(const uint4*)&AL[go];
    }

    f32x4 acc[2];
    acc[0] = (f32x4){0.f, 0.f, 0.f, 0.f};
    acc[1] = (f32x4){0.f, 0.f, 0.f, 0.f};

    // ---- Wout GEMM: hf[32][128] = A[32][256] @ Wout
    for (int kc = 0; kc < 256; kc += 64) {
        __syncthreads();
        for (int u = tid; u < 1024; u += 512) {
            int n = u >> 3, g = u & 7;
            size_t go = (size_t)(W_WOUT) + (size_t)n * 256 + kc + g * 8;
            *(uint4*)&BsH[n][g * 8] = *(const uint4*)&wH[go];
            *(uint4*)&BsL[n][g * 8] = *(const uint4*)&wL[go];
        }
        __syncthreads();
#pragma unroll
        for (int ks_ = 0; ks_ < 64; ks_ += 32) {
            const int kka = kc + ks_ + q * 8;
            const int kkb = ks_ + q * 8;
            bf16x8 ah = *(const bf16x8*)&AsH[wm * 16 + ln][kka];
            bf16x8 al = *(const bf16x8*)&AsL[wm * 16 + ln][kka];
#pragma unroll
            for (int cb = 0; cb < 2; ++cb) {
                bf16x8 bh = *(const bf16x8*)&BsH[wn * 32 + cb * 16 + ln][kkb];
                bf16x8 bl = *(const bf16x8*)&BsL[wn * 32 + cb * 16 + ln][kkb];
                acc[cb] = __builtin_amdgcn_mfma_f32_16x16x32_bf16(ah, bh, acc[cb], 0, 0, 0);
                acc[cb] = __builtin_amdgcn_mfma_f32_16x16x32_bf16(ah, bl, acc[cb], 0, 0, 0);
                acc[cb] = __builtin_amdgcn_mfma_f32_16x16x32_bf16(al, bh, acc[cb], 0, 0, 0);
            }
        }
    }
    __syncthreads();   // As reads done -> safe to overlay hf
    // epilogue 1: + bout + h_ residual -> hf in LDS (hi/lo)
#pragma unroll
    for (int cb = 0; cb < 2; ++cb)
#pragma unroll
        for (int r = 0; r < 4; ++r) {
            int row = wm * 16 + q * 4 + r;
            int col = wn * 32 + cb * 16 + ln;
            float v = acc[cb][r] + bout[col] + h_[(size_t)(mb + row) * 128 + col];
            ushort hh, ll; f2hl(v, &hh, &ll);
            hfH[row][col] = hh;
            hfL[row][col] = ll;
        }
    __syncthreads();

    // ---- unembed GEMM: out[32][128] = hf[32][128] @ pu^T (+pu_b +ks, scattered)
    f32x4 acc2[2];
    acc2[0] = (f32x4){0.f, 0.f, 0.f, 0.f};
    acc2[1] = (f32x4){0.f, 0.f, 0.f, 0.f};
    for (int kc = 0; kc < 128; kc += 64) {
        __syncthreads();
        for (int u = tid; u < 1024; u += 512) {
            int n = u >> 3, g = u & 7;
            size_t go = (size_t)(W_PU) + (size_t)n * 128 + kc + g * 8;
            *(uint4*)&BsH[n][g * 8] = *(const uint4*)&wH[go];
            *(uint4*)&BsL[n][g * 8] = *(const uint4*)&wL[go];
        }
        __syncthreads();
#pragma unroll
        for (int ks_ = 0; ks_ < 64; ks_ += 32) {
            const int kka = kc + ks_ + q * 8;
            const int kkb = ks_ + q * 8;
            bf16x8 ah = *(const bf16x8*)&hfH[wm * 16 + ln][kka];
            bf16x8 al = *(const bf16x8*)&hfL[wm * 16 + ln][kka];
#pragma unroll
            for (int cb = 0; cb < 2; ++cb) {
                bf16x8 bh = *(const bf16x8*)&BsH[wn * 32 + cb * 16 + ln][kkb];
                bf16x8 bl = *(const bf16x8*)&BsL[wn * 32 + cb * 16 + ln][kkb];
                acc2[cb] = __builtin_amdgcn_mfma_f32_16x16x32_bf16(ah, bh, acc2[cb], 0, 0, 0);
                acc2[cb] = __builtin_amdgcn_mfma_f32_16x16x32_bf16(ah, bl, acc2[cb], 0, 0, 0);
                acc2[cb] = __builtin_amdgcn_mfma_f32_16x16x32_bf16(al, bh, acc2[cb], 0, 0, 0);
            }
        }
    }
#pragma unroll
    for (int cb = 0; cb < 2; ++cb)
#pragma unroll
        for (int r = 0; r < 4; ++r) {
            int l = mb + wm * 16 + q * 4 + r;
            int col = wn * 32 + cb * 16 + ln;
            int xg = l >> 8, yg = (l >> 3) & 31, zg = l & 7;
            int cch = col >> 3, ijk = col & 7;
            int i2 = (ijk >> 2) & 1, j2 = (ijk >> 1) & 1, k2 = ijk & 1;
            size_t idx = (size_t)((cch * 64 + 2 * xg + i2) * 64 + (2 * yg + j2)) * 16 + 2 * zg + k2;
            out[idx] = acc2[cb][r] + pu_b[cch] + ks[idx];
        }
}

// ---------------------------------------------------------------------------
extern "C" void kernel_launch(void* const* d_in, const int* in_sizes, int n_in,
                              void* d_out, int out_size, void* d_ws, size_t ws_size,
                              hipStream_t stream) {
    const float* ks    = (const float*)d_in[0];
    const float* mask  = (const float*)d_in[1];
    const float* pe_w  = (const float*)d_in[2];
    const float* pe_b  = (const float*)d_in[3];
    const float* pu_w  = (const float*)d_in[4];
    const float* pu_b  = (const float*)d_in[5];
    const float* ln_g  = (const float*)d_in[6];
    const float* ln_b  = (const float*)d_in[7];
    const float* fn_g  = (const float*)d_in[8];
    const float* fn_b  = (const float*)d_in[9];
    const float* cond_band = (const float*)d_in[10];
    const float* cond_rad  = (const float*)d_in[11];
    const float* cond_mask = (const float*)d_in[12];
    const float* Win   = (const float*)d_in[13];
    const float* bin_  = (const float*)d_in[14];
    const float* convw = (const float*)d_in[15];
    const float* convb = (const float*)d_in[16];
    const float* Wx    = (const float*)d_in[17];
    const float* Wdt   = (const float*)d_in[18];
    const float* bdt   = (const float*)d_in[19];
    const float* Alog  = (const float*)d_in[20];
    const float* Dp    = (const float*)d_in[21];
    const float* Wout  = (const float*)d_in[22];
    const float* bout  = (const float*)d_in[23];
    const float* edt   = (const float*)d_in[24];
    const float* eB    = (const float*)d_in[25];
    const float* eC    = (const float*)d_in[26];
    const float* wr    = (const float*)d_in[27];
    const float* wm    = (const float*)d_in[28];
    float* out = (float*)d_out;

    char* base = (char*)d_ws;
    size_t o = 0;
    auto alloc = [&](size_t bytes) { char* p = base + o; o += (bytes + 255) & ~(size_t)255; return p; };
    float*  mbuf = (float*)alloc(32768);
    ushort* wH   = (ushort*)alloc(W_TOT * 2);
    ushort* wL   = (ushort*)alloc(W_TOT * 2);
    float*  h_   = (float*)alloc(4194304);
    ushort* hnH  = (ushort*)alloc(2097152);
    ushort* hnL  = (ushort*)alloc(2097152);
    float*  xp   = (float*)alloc(8388608);
    float*  sz   = (float*)alloc(8388608);
    float*  xc   = (float*)alloc(8388608);
    float*  dt   = (float*)alloc(8388608);
    float*  Bm   = (float*)alloc(524288);
    float*  Cm   = (float*)alloc(524288);
    float*  Hb   = (float*)alloc((size_t)2 * NCh * 4096 * 4);    // 16 MB
    float*  Hpp  = (float*)alloc((size_t)2 * NCh * 4096 * 4);    // 16 MB
    float*  sdtb = (float*)alloc((size_t)NCh * 256 * 4);         // 512 KB
    float*  cumsdtb = (float*)alloc((size_t)2 * NCh * 256 * 4);  // 1 MB
    float*  segq    = (float*)alloc((size_t)2 * NSEG * 4096 * 4);
    float*  segsdt  = (float*)alloc((size_t)2 * NSEG * 256 * 4);
    float*  segpre  = (float*)alloc((size_t)2 * NSEG * 4096 * 4);
    ushort* AHo  = (ushort*)alloc(4194304);
    ushort* ALo  = (ushort*)alloc(4194304);

    prep_k<<<864, 256, 0, stream>>>(pe_w, Win, Wx, Wdt, Wout, pu_w, mask, wH, wL, mbuf);
    embed_ln_k<<<512, 256, 0, stream>>>(ks, wH, wL, pe_b, cond_band, cond_rad, cond_mask, mbuf,
                                        ln_g, ln_b, fn_g, fn_b, h_, hnH, hnL);
    win_k<<<dim3(128, 8), 256, 0, stream>>>(hnH, hnL, wH, wL, bin_, xp, sz);
    proj_k<<<256, 512, 0, stream>>>(xp, convw, convb, wH, wL, bdt, mbuf, edt, eB, eC, wr, wm,
                                    xc, dt, Bm, Cm);
    scan0_k<<<dim3(NCh, 2), 256, 0, stream>>>(dt, xc, Bm, Alog, Hb, sdtb);
    combine1_k<<<256, 256, 0, stream>>>(Hb, sdtb, Alog, Hpp, cumsdtb, segq, segsdt);
    combine2_k<<<128, 64, 0, stream>>>(segq, segsdt, Alog, segpre);
    scan1g_k<<<NCh, 512, 0, stream>>>(dt, xc, Bm, Cm, Alog, Hpp, cumsdtb, segpre, sz, Dp, AHo, ALo);
    wu_k<<<256, 512, 0, stream>>>(AHo, ALo, wH, wL, bout, h_, pu_b, ks, out);
}

// Round 6
// 240.228 us; speedup vs baseline: 1.5398x; 1.0364x over previous
//
#include <hip/hip_runtime.h>
#include <hip/hip_bf16.h>

#define L_TOK 8192
#define NCh 512   // scan chunks
#define CLh 16    // chunk length
#define NSEG 8    // segments for chunk-combine
#define CPS (NCh / NSEG)   // chunks per segment = 64
#define LOG2E 1.44269504088896f

typedef short bf16x8 __attribute__((ext_vector_type(8)));
typedef float f32x4 __attribute__((ext_vector_type(4)));

static __device__ __forceinline__ float nexp2(float x) {
#if __has_builtin(__builtin_amdgcn_exp2f)
    return __builtin_amdgcn_exp2f(x);
#else
    return exp2f(x);
#endif
}
static __device__ __forceinline__ float sigm(float x) {
    return 1.f / (1.f + nexp2(-x * LOG2E));
}
static __device__ __forceinline__ ushort f2bf(float x) {
    union { float f; uint u; } v; v.f = x;
    uint r = v.u + 0x7fffu + ((v.u >> 16) & 1u);
    return (ushort)(r >> 16);
}
static __device__ __forceinline__ float bf2f(ushort h) {
    union { float f; uint u; } v; v.u = ((uint)h) << 16;
    return v.f;
}
static __device__ __forceinline__ void f2hl(float x, ushort* hi, ushort* lo) {
    ushort h = f2bf(x);
    *hi = h;
    *lo = f2bf(x - bf2f(h));
}

// weight regions in wH/wL (ushort elems), all K-major [n][k]:
#define W_PE   0
#define W_WIN  16384
#define W_WOUT 81920
#define W_PU   114688
#define W_PROJ 131072
#define W_TOT  212992

// ---------------------------------------------------------------------------
// MERGED embed+prep. Blocks 0..511: embed GEMM (+pe_b+cond) -> LN2, reading
// pe_w f32 directly (it is already [n][k]) + inline mask-pool -> no dependency
// on the prep path. Blocks 512..1375: weight hi/lo conversion + maskpool
// (consumed by later kernels only). Saves one launch boundary.
__global__ __launch_bounds__(256) void embed_ln_k(const float* __restrict__ ks,
                                                  const float* __restrict__ pe_w,
                                                  const float* __restrict__ Win,
                                                  const float* __restrict__ Wx, const float* __restrict__ Wdt,
                                                  const float* __restrict__ Wout, const float* __restrict__ pu_w,
                                                  const float* __restrict__ mask,
                                                  const float* __restrict__ pe_b, const float* __restrict__ cond_band,
                                                  const float* __restrict__ cond_rad, const float* __restrict__ cond_mask,
                                                  const float* __restrict__ ln_g, const float* __restrict__ ln_b,
                                                  const float* __restrict__ fn_g, const float* __restrict__ fn_b,
                                                  ushort* __restrict__ wH, ushort* __restrict__ wL,
                                                  float* __restrict__ mbuf,
                                                  float* __restrict__ h_,
                                                  ushort* __restrict__ hnH, ushort* __restrict__ hnL) {
    const int tid = threadIdx.x;
    if (blockIdx.x >= 512) {          // ---- prep path
        int b = blockIdx.x - 512;     // 0..863
        if (b >= 832) {               // maskpool
            int l = (b - 832) * 256 + tid;
            int xg = l >> 8, yg = (l >> 3) & 31, zg = l & 7;
            float s = 0.f;
            for (int i2 = 0; i2 < 2; ++i2)
                for (int j2 = 0; j2 < 2; ++j2)
                    for (int k2 = 0; k2 < 2; ++k2)
                        s += mask[(2 * xg + i2) * 1024 + (2 * yg + j2) * 16 + 2 * zg + k2];
            s *= 0.125f;
            mbuf[l] = fminf(fmaxf(s, 0.f), 1.f);
            return;
        }
        int i = b * 256 + tid;  // < 212992
        float v;
        if (i < 16384) {
            v = pe_w[i];
        } else if (i < 81920) {
            int j = i - 16384; int n = j >> 7, k = j & 127;
            v = Win[k * 512 + n];
        } else if (i < 114688) {
            int j = i - 81920; int n = j >> 8, k = j & 255;
            v = Wout[k * 128 + n];
        } else if (i < 131072) {
            int j = i - 114688; int n = j >> 7, k = j & 127;
            v = pu_w[k * 128 + n];
        } else {
            int j = i - 131072; int n = j >> 8, k = j & 255;
            if (n < 256) {
                float s = 0.f;
#pragma unroll
                for (int r = 0; r < 8; ++r) s += Wx[k * 40 + r] * Wdt[r * 256 + n];
                v = s;
            } else if (n < 288) {
                v = Wx[k * 40 + 8 + (n - 256)];
            } else {
                v = 0.f;
            }
        }
        ushort h, lo; f2hl(v, &h, &lo);
        wH[i] = h; wL[i] = lo;
        return;
    }

    // ---- embed path
    __shared__ __align__(16) char smem[50176];
    __shared__ float mpool[16];
    ushort (*AsH)[72] = (ushort(*)[72])(smem);             // 16x72
    ushort (*AsL)[72] = (ushort(*)[72])(smem + 2304);
    ushort (*BsH)[72] = (ushort(*)[72])(smem + 4608);      // 128x72
    ushort (*BsL)[72] = (ushort(*)[72])(smem + 23040);     // ..41472
    float*  ksb       = (float*)(smem + 41472);            // 2176 floats (128 segs x 17)
    float  (*Cs)[132] = (float(*)[132])(smem);             // 16x132 (reuse after MFMA)

    const int lane = tid & 63, wn = tid >> 6;
    const int ln = lane & 15, q = lane >> 4;
    const int mb = blockIdx.x * 16;
    const int xg = mb >> 8, yg0 = (mb >> 3) & 31;

    // coalesced stage of the block's kspace footprint:
    for (int v = tid; v < 512; v += 256) {
        int seg = v >> 2, zq = v & 3;
        int cc = seg >> 3, i2 = (seg >> 2) & 1, yy = seg & 3;
        float4 t4 = *(const float4*)&ks[cc * 65536 + (2 * xg + i2) * 1024 + (2 * yg0 + yy) * 16 + zq * 4];
        int la = seg * 17 + zq * 4;
        ksb[la] = t4.x; ksb[la + 1] = t4.y; ksb[la + 2] = t4.z; ksb[la + 3] = t4.w;
    }
    if (tid < 16) {   // inline mask pool for this block's 16 rows
        int l = mb + tid;
        int xg2 = l >> 8, yg2 = (l >> 3) & 31, zg2 = l & 7;
        float s = 0.f;
        for (int i2 = 0; i2 < 2; ++i2)
            for (int j2 = 0; j2 < 2; ++j2)
                for (int k2 = 0; k2 < 2; ++k2)
                    s += mask[(2 * xg2 + i2) * 1024 + (2 * yg2 + j2) * 16 + 2 * zg2 + k2];
        mpool[tid] = fminf(fmaxf(s * 0.125f, 0.f), 1.f);
    }

    f32x4 acc[2];
    acc[0] = (f32x4){0.f, 0.f, 0.f, 0.f};
    acc[1] = (f32x4){0.f, 0.f, 0.f, 0.f};

    for (int kc = 0; kc < 128; kc += 64) {
        __syncthreads();
        for (int u = tid; u < 1024; u += 256) {
            int r = u >> 6, kk = u & 63;
            int k = kc + kk;
            int cc = k >> 3, ijk = k & 7;
            int i2 = (ijk >> 2) & 1, j2 = (ijk >> 1) & 1, k2 = ijk & 1;
            int seg = (cc * 2 + i2) * 4 + (r >> 3) * 2 + j2;
            float v = ksb[seg * 17 + (r & 7) * 2 + k2];
            ushort hh, ll; f2hl(v, &hh, &ll);
            AsH[r][kk] = hh; AsL[r][kk] = ll;
        }
        for (int u = tid; u < 1024; u += 256) {
            int n = u >> 3, g = u & 7;
            const float* pw = &pe_w[n * 128 + kc + g * 8];
            float4 p0 = *(const float4*)pw;
            float4 p1 = *(const float4*)(pw + 4);
            union { ushort us[8]; uint4 v4; } hh, ll;
            f2hl(p0.x, &hh.us[0], &ll.us[0]); f2hl(p0.y, &hh.us[1], &ll.us[1]);
            f2hl(p0.z, &hh.us[2], &ll.us[2]); f2hl(p0.w, &hh.us[3], &ll.us[3]);
            f2hl(p1.x, &hh.us[4], &ll.us[4]); f2hl(p1.y, &hh.us[5], &ll.us[5]);
            f2hl(p1.z, &hh.us[6], &ll.us[6]); f2hl(p1.w, &hh.us[7], &ll.us[7]);
            *(uint4*)&BsH[n][g * 8] = hh.v4;
            *(uint4*)&BsL[n][g * 8] = ll.v4;
        }
        __syncthreads();
#pragma unroll
        for (int ks_ = 0; ks_ < 64; ks_ += 32) {
            const int kk = ks_ + q * 8;
            bf16x8 ah = *(const bf16x8*)&AsH[ln][kk];
            bf16x8 al = *(const bf16x8*)&AsL[ln][kk];
#pragma unroll
            for (int cb = 0; cb < 2; ++cb) {
                bf16x8 bh = *(const bf16x8*)&BsH[wn * 32 + cb * 16 + ln][kk];
                bf16x8 bl = *(const bf16x8*)&BsL[wn * 32 + cb * 16 + ln][kk];
                acc[cb] = __builtin_amdgcn_mfma_f32_16x16x32_bf16(ah, bh, acc[cb], 0, 0, 0);
                acc[cb] = __builtin_amdgcn_mfma_f32_16x16x32_bf16(ah, bl, acc[cb], 0, 0, 0);
                acc[cb] = __builtin_amdgcn_mfma_f32_16x16x32_bf16(al, bh, acc[cb], 0, 0, 0);
            }
        }
    }
    __syncthreads();
#pragma unroll
    for (int cb = 0; cb < 2; ++cb) {
#pragma unroll
        for (int r = 0; r < 4; ++r) {
            int row = q * 4 + r;
            int col = wn * 32 + cb * 16 + ln;
            int l = mb + row;
            float rho = (float)l * (1.0f / 8191.0f);
            int band = min(7, (int)(rho * 8.0f));
            Cs[row][col] = acc[cb][r] + pe_b[col] + cond_band[band * 128 + col]
                           + rho * cond_rad[col] + mpool[row] * cond_mask[col];
        }
    }
    __syncthreads();
    {
        int row = tid >> 4, j = tid & 15;
        int l = mb + row;
        float v8[8];
        float s = 0.f, s2 = 0.f;
#pragma unroll
        for (int i = 0; i < 8; ++i) {
            float v = Cs[row][j * 8 + i];
            v8[i] = v; s += v; s2 += v * v;
        }
#pragma unroll
        for (int o = 1; o < 16; o <<= 1) { s += __shfl_xor(s, o, 16); s2 += __shfl_xor(s2, o, 16); }
        float mu = s * (1.f / 128.f);
        float var = s2 * (1.f / 128.f) - mu * mu;
        float rstd = rsqrtf(fmaxf(var, 0.f) + 1e-5f);
        float hv[8];
        s = 0.f; s2 = 0.f;
#pragma unroll
        for (int i = 0; i < 8; ++i) {
            int col = j * 8 + i;
            float h = (v8[i] - mu) * rstd * ln_g[col] + ln_b[col];
            hv[i] = h; s += h; s2 += h * h;
        }
#pragma unroll
        for (int i = 0; i < 8; i += 4)
            *(float4*)&h_[(size_t)l * 128 + j * 8 + i] = make_float4(hv[i], hv[i + 1], hv[i + 2], hv[i + 3]);
#pragma unroll
        for (int o = 1; o < 16; o <<= 1) { s += __shfl_xor(s, o, 16); s2 += __shfl_xor(s2, o, 16); }
        mu = s * (1.f / 128.f);
        var = s2 * (1.f / 128.f) - mu * mu;
        rstd = rsqrtf(fmaxf(var, 0.f) + 1e-5f);
        union { ushort u[8]; uint4 v4; } oh, ol;
#pragma unroll
        for (int i = 0; i < 8; ++i) {
            int col = j * 8 + i;
            float o2 = (hv[i] - mu) * rstd * fn_g[col] + fn_b[col];
            ushort hh, ll; f2hl(o2, &hh, &ll);
            oh.u[i] = hh; ol.u[i] = ll;
        }
        *(uint4*)&hnH[(size_t)l * 128 + j * 8] = oh.v4;
        *(uint4*)&hnL[(size_t)l * 128 + j * 8] = ol.v4;
    }
}

// ---------------------------------------------------------------------------
// Win GEMM: 64x64 tiles, grid (128,8) = 1024 blocks. xp raw / sz silu split.
__global__ __launch_bounds__(256) void win_k(const ushort* __restrict__ Ah, const ushort* __restrict__ Al,
                                             const ushort* __restrict__ wH, const ushort* __restrict__ wL,
                                             const float* __restrict__ bin_,
                                             float* __restrict__ xp, float* __restrict__ sz) {
    __shared__ ushort AsH[64][72], AsL[64][72];
    __shared__ ushort BsH[64][72], BsL[64][72];
    const int tid = threadIdx.x;
    const int lane = tid & 63, wave = tid >> 6;
    const int wm = wave & 1, wn = wave >> 1;
    const int ln = lane & 15, q = lane >> 4;
    const int mb = blockIdx.x * 64, nb = blockIdx.y * 64;

    f32x4 acc[2][2];
#pragma unroll
    for (int rb = 0; rb < 2; ++rb)
#pragma unroll
        for (int cb = 0; cb < 2; ++cb) acc[rb][cb] = (f32x4){0.f, 0.f, 0.f, 0.f};

    for (int kc = 0; kc < 128; kc += 64) {
        __syncthreads();
        for (int u = tid; u < 512; u += 256) {
            int r = u >> 3, g = u & 7;
            size_t go = (size_t)(mb + r) * 128 + kc + g * 8;
            *(uint4*)&AsH[r][g * 8] = *(const uint4*)&Ah[go];
            *(uint4*)&AsL[r][g * 8] = *(const uint4*)&Al[go];
        }
        for (int u = tid; u < 512; u += 256) {
            int n = u >> 3, g = u & 7;
            size_t go = (size_t)(W_WIN) + (size_t)(nb + n) * 128 + kc + g * 8;
            *(uint4*)&BsH[n][g * 8] = *(const uint4*)&wH[go];
            *(uint4*)&BsL[n][g * 8] = *(const uint4*)&wL[go];
        }
        __syncthreads();
#pragma unroll
        for (int ks_ = 0; ks_ < 64; ks_ += 32) {
            const int kk = ks_ + q * 8;
            bf16x8 ah[2], al[2], bh[2], bl[2];
#pragma unroll
            for (int rb = 0; rb < 2; ++rb) {
                ah[rb] = *(const bf16x8*)&AsH[wm * 32 + rb * 16 + ln][kk];
                al[rb] = *(const bf16x8*)&AsL[wm * 32 + rb * 16 + ln][kk];
            }
#pragma unroll
            for (int cb = 0; cb < 2; ++cb) {
                bh[cb] = *(const bf16x8*)&BsH[wn * 32 + cb * 16 + ln][kk];
                bl[cb] = *(const bf16x8*)&BsL[wn * 32 + cb * 16 + ln][kk];
            }
#pragma unroll
            for (int rb = 0; rb < 2; ++rb)
#pragma unroll
                for (int cb = 0; cb < 2; ++cb) {
                    acc[rb][cb] = __builtin_amdgcn_mfma_f32_16x16x32_bf16(ah[rb], bh[cb], acc[rb][cb], 0, 0, 0);
                    acc[rb][cb] = __builtin_amdgcn_mfma_f32_16x16x32_bf16(ah[rb], bl[cb], acc[rb][cb], 0, 0, 0);
                    acc[rb][cb] = __builtin_amdgcn_mfma_f32_16x16x32_bf16(al[rb], bh[cb], acc[rb][cb], 0, 0, 0);
                }
        }
    }
#pragma unroll
    for (int rb = 0; rb < 2; ++rb)
#pragma unroll
        for (int cb = 0; cb < 2; ++cb)
#pragma unroll
            for (int r = 0; r < 4; ++r) {
                int l = mb + wm * 32 + rb * 16 + q * 4 + r;
                int col = nb + wn * 32 + cb * 16 + ln;
                float v = acc[rb][cb][r] + bin_[col];
                if (col < 256) {
                    xp[(size_t)l * 256 + col] = v;
                } else {
                    sz[(size_t)l * 256 + (col - 256)] = v * sigm(v);
                }
            }
}

// ---------------------------------------------------------------------------
// proj GEMM with conv+SiLU fused in front. 512 threads, grid 256 (32 rows each).
// B tile register-double-buffered: next tile's loads issue before the MFMA
// phase, so global-load latency hides under compute.
__global__ __launch_bounds__(512) void proj_k(const float* __restrict__ xp,
                                              const float* __restrict__ convw, const float* __restrict__ convb,
                                              const ushort* __restrict__ wH, const ushort* __restrict__ wL,
                                              const float* __restrict__ bdt, const float* __restrict__ mbuf,
                                              const float* __restrict__ edt, const float* __restrict__ eB,
                                              const float* __restrict__ eC, const float* __restrict__ wr,
                                              const float* __restrict__ wm,
                                              float* __restrict__ xc, float* __restrict__ dt,
                                              float* __restrict__ Bm, float* __restrict__ Cm) {
    __shared__ __align__(16) char smem[52224];
    ushort (*AsH)[264] = (ushort(*)[264])(smem);            // 32x264x2 = 16896
    ushort (*AsL)[264] = (ushort(*)[264])(smem + 16896);    // ..33792
    ushort (*BsH)[72]  = (ushort(*)[72])(smem + 33792);     // 64x72x2 = 9216
    ushort (*BsL)[72]  = (ushort(*)[72])(smem + 43008);     // ..52224
    const int tid = threadIdx.x;
    const int mb = blockIdx.x * 32;

    // ---- conv (4-tap causal) + SiLU, sliding window; -> xc global + LDS hi/lo
    {
        const int cg = tid & 63;       // col group: cols cg*4..+3
        const int rg = tid >> 6;       // row group: rows rg*4..+3
        const int c0 = cg * 4;
        float4 cb4 = *(const float4*)&convb[c0];
        float4 cw0 = *(const float4*)&convw[(c0 + 0) * 4];
        float4 cw1 = *(const float4*)&convw[(c0 + 1) * 4];
        float4 cw2 = *(const float4*)&convw[(c0 + 2) * 4];
        float4 cw3 = *(const float4*)&convw[(c0 + 3) * 4];
        const int lbase = mb + rg * 4;
        float4 zero = make_float4(0.f, 0.f, 0.f, 0.f);
        float4 x0 = (lbase - 3 >= 0) ? *(const float4*)&xp[(size_t)(lbase - 3) * 256 + c0] : zero;
        float4 x1 = (lbase - 2 >= 0) ? *(const float4*)&xp[(size_t)(lbase - 2) * 256 + c0] : zero;
        float4 x2 = (lbase - 1 >= 0) ? *(const float4*)&xp[(size_t)(lbase - 1) * 256 + c0] : zero;
#pragma unroll
        for (int rr = 0; rr < 4; ++rr) {
            int l = lbase + rr;
            float4 x3 = *(const float4*)&xp[(size_t)l * 256 + c0];
            float o0 = cb4.x + x0.x * cw0.x + x1.x * cw0.y + x2.x * cw0.z + x3.x * cw0.w;
            float o1 = cb4.y + x0.y * cw1.x + x1.y * cw1.y + x2.y * cw1.z + x3.y * cw1.w;
            float o2 = cb4.z + x0.z * cw2.x + x1.z * cw2.y + x2.z * cw2.z + x3.z * cw2.w;
            float o3 = cb4.w + x0.w * cw3.x + x1.w * cw3.y + x2.w * cw3.z + x3.w * cw3.w;
            o0 *= sigm(o0); o1 *= sigm(o1); o2 *= sigm(o2); o3 *= sigm(o3);
            *(float4*)&xc[(size_t)l * 256 + c0] = make_float4(o0, o1, o2, o3);
            union { ushort u[4]; uint2 v2; } hh, ll;
            f2hl(o0, &hh.u[0], &ll.u[0]); f2hl(o1, &hh.u[1], &ll.u[1]);
            f2hl(o2, &hh.u[2], &ll.u[2]); f2hl(o3, &hh.u[3], &ll.u[3]);
            int row = l - mb;
            *(uint2*)&AsH[row][c0] = hh.v2;
            *(uint2*)&AsL[row][c0] = ll.v2;
            x0 = x1; x1 = x2; x2 = x3;
        }
    }
    // preload first B tile into registers (independent of LDS)
    const int pn = tid >> 3, pg = tid & 7;
    uint4 regH = *(const uint4*)&wH[(size_t)W_PROJ + (size_t)pn * 256 + pg * 8];
    uint4 regL = *(const uint4*)&wL[(size_t)W_PROJ + (size_t)pn * 256 + pg * 8];
    __syncthreads();

    // ---- GEMM 32x64 per iter, 5 iters, 8 waves
    const int lane = tid & 63, wave = tid >> 6;
    const int wm2 = wave & 1, wn4 = wave >> 1;
    const int ln = lane & 15, q = lane >> 4;
    for (int it = 0; it < 5; ++it) {
        int nb = it * 64;
        f32x4 acc = (f32x4){0.f, 0.f, 0.f, 0.f};
        for (int kci = 0; kci < 4; ++kci) {
            int kc = kci * 64;
            __syncthreads();           // prior MFMA done reading Bs
            *(uint4*)&BsH[pn][pg * 8] = regH;
            *(uint4*)&BsL[pn][pg * 8] = regL;
            int s = it * 4 + kci;
            if (s < 19) {              // issue next tile's loads early
                int s2 = s + 1;
                int nb2 = (s2 >> 2) * 64, kc2 = (s2 & 3) * 64;
                size_t go = (size_t)W_PROJ + (size_t)(nb2 + pn) * 256 + kc2 + pg * 8;
                regH = *(const uint4*)&wH[go];
                regL = *(const uint4*)&wL[go];
            }
            __syncthreads();           // Bs visible
#pragma unroll
            for (int ks_ = 0; ks_ < 64; ks_ += 32) {
                const int kka = kc + ks_ + q * 8;
                const int kkb = ks_ + q * 8;
                bf16x8 ah = *(const bf16x8*)&AsH[wm2 * 16 + ln][kka];
                bf16x8 al = *(const bf16x8*)&AsL[wm2 * 16 + ln][kka];
                bf16x8 bh = *(const bf16x8*)&BsH[wn4 * 16 + ln][kkb];
                bf16x8 bl = *(const bf16x8*)&BsL[wn4 * 16 + ln][kkb];
                acc = __builtin_amdgcn_mfma_f32_16x16x32_bf16(ah, bh, acc, 0, 0, 0);
                acc = __builtin_amdgcn_mfma_f32_16x16x32_bf16(ah, bl, acc, 0, 0, 0);
                acc = __builtin_amdgcn_mfma_f32_16x16x32_bf16(al, bh, acc, 0, 0, 0);
            }
        }
#pragma unroll
        for (int r = 0; r < 4; ++r) {
            int l = mb + wm2 * 16 + q * 4 + r;
            int col = nb + wn4 * 16 + ln;
            float v = acc[r];
            float rho = (float)l * (1.0f / 8191.0f);
            int band = min(7, (int)(rho * 8.0f));
            float mv = mbuf[l];
            if (col < 256) {
                float sc0 = 2.0f * sigm(edt[band] + wr[0] * rho + wm[0] * mv);
                float v2 = v + bdt[col];
                float sp = (v2 > 20.f) ? v2 : log1pf(expf(v2));
                dt[(size_t)l * 256 + col] = sp * sc0;
            } else if (col < 272) {
                float sc1 = 2.0f * sigm(eB[band] + wr[1] * rho + wm[1] * mv);
                Bm[(size_t)l * 16 + (col - 256)] = v * sc1;
            } else if (col < 288) {
                float sc2 = 2.0f * sigm(eC[band] + wr[2] * rho + wm[2] * mv);
                Cm[(size_t)l * 16 + (col - 272)] = v * sc2;
            }
        }
    }
}

// ---------------------------------------------------------------------------
// scan phase 0: chunk-local end states -> Hb, fwd chunk dt-sums -> sdtb
// Both dirs in one 512-thread block (bms staged once; dt/xc L1-shared).
__global__ __launch_bounds__(512) void scan0_k(const float* __restrict__ dt, const float* __restrict__ xc,
                                               const float* __restrict__ Bm, const float* __restrict__ Alog,
                                               float* __restrict__ Hb, float* __restrict__ sdtb) {
    const int c = blockIdx.x;
    const int tid = threadIdx.x;
    const int dir = tid >> 8, e = tid & 255;
    __shared__ float bms[CLh][16];
    for (int idx = tid; idx < CLh * 16; idx += 512)
        bms[idx >> 4][idx & 15] = Bm[c * (CLh * 16) + idx];
    float A2[16], iv[16], h[16];
#pragma unroll
    for (int n = 0; n < 16; ++n) {
        float ea = nexp2(Alog[e * 16 + n] * LOG2E);
        A2[n] = -ea * LOG2E;
        iv[n] = -1.0f / ea;
        h[n] = 0.f;
    }
    const int base = c * CLh;
    float cu[8], cx[8], nu[8], nx[8];
#pragma unroll
    for (int j = 0; j < 8; ++j) {
        int p = dir ? (CLh - 1 - j) : j;
        cu[j] = dt[(size_t)(base + p) * 256 + e];
        cx[j] = xc[(size_t)(base + p) * 256 + e];
    }
    __syncthreads();
    float sdt = 0.f;
#pragma unroll
    for (int g = 0; g < CLh / 8; ++g) {
        if (g + 1 < CLh / 8) {
#pragma unroll
            for (int j = 0; j < 8; ++j) {
                int s = (g + 1) * 8 + j;
                int p = dir ? (CLh - 1 - s) : s;
                nu[j] = dt[(size_t)(base + p) * 256 + e];
                nx[j] = xc[(size_t)(base + p) * 256 + e];
            }
        }
#pragma unroll
        for (int j = 0; j < 8; ++j) {
            float u = cu[j], xv = cx[j];
            int s = g * 8 + j;
            int p = dir ? (CLh - 1 - s) : s;
            union { float4 v[4]; float f[16]; } bb;
            const float4* bp = (const float4*)&bms[p][0];
            bb.v[0] = bp[0]; bb.v[1] = bp[1]; bb.v[2] = bp[2]; bb.v[3] = bp[3];
#pragma unroll
            for (int n = 0; n < 16; ++n) {
                float a = nexp2(A2[n] * u);
                float w = xv * bb.f[n] * iv[n];
                h[n] = a * (h[n] + w) - w;
            }
            sdt += u;
        }
#pragma unroll
        for (int j = 0; j < 8; ++j) { cu[j] = nu[j]; cx[j] = nx[j]; }
    }
    const size_t hofs = (size_t)(dir * NCh + c) * 4096 + e * 16;
#pragma unroll
    for (int j = 0; j < 4; ++j)
        *(float4*)&Hb[hofs + 4 * j] = make_float4(h[4 * j], h[4 * j + 1], h[4 * j + 2], h[4 * j + 3]);
    if (dir == 0) sdtb[c * 256 + e] = sdt;
}

// ---------------------------------------------------------------------------
// chunk combine, level 1: within-segment partial prefixes.
// 65536 threads = 8 seg x 2 dir x 4096 en; 64 serial steps each.
__global__ __launch_bounds__(256) void combine1_k(const float* __restrict__ Hb, const float* __restrict__ sdtb,
                                                  const float* __restrict__ Alog,
                                                  float* __restrict__ Hpp, float* __restrict__ cumsdtb,
                                                  float* __restrict__ segq, float* __restrict__ segsdt) {
    const int gid = blockIdx.x * 256 + threadIdx.x;   // < 65536
    const int seg = gid >> 13;                        // 0..7
    const int r = gid & 8191;
    const int d1 = r >> 12, en = r & 4095, e1 = en >> 4;
    const float A2e = -nexp2(Alog[en] * LOG2E) * LOG2E;
    float hi = 0.f, cum = 0.f;
    for (int k = 0; k < CPS; ++k) {
        const int pos = seg * CPS + k;
        const int c2 = d1 ? (NCh - 1 - pos) : pos;
        const size_t o2 = (size_t)(d1 * NCh + c2) * 4096 + en;
        const float sv = sdtb[c2 * 256 + e1];
        Hpp[o2] = hi;
        if ((en & 15) == 0) cumsdtb[(d1 * NCh + c2) * 256 + e1] = cum;
        hi = nexp2(A2e * sv) * hi + Hb[o2];
        cum += sv;
    }
    segq[(d1 * NSEG + seg) * 4096 + en] = hi;
    if ((en & 15) == 0) segsdt[(d1 * NSEG + seg) * 256 + e1] = cum;
}

// chunk combine, level 2: 8-step scan over segment summaries -> segpre.
__global__ __launch_bounds__(64) void combine2_k(const float* __restrict__ segq, const float* __restrict__ segsdt,
                                                 const float* __restrict__ Alog, float* __restrict__ segpre) {
    const int gid = blockIdx.x * 64 + threadIdx.x;    // < 8192
    const int d1 = gid >> 12, en = gid & 4095, e1 = en >> 4;
    const float A2e = -nexp2(Alog[en] * LOG2E) * LOG2E;
    float hi = 0.f;
#pragma unroll
    for (int s = 0; s < NSEG; ++s) {
        segpre[(d1 * NSEG + s) * 4096 + en] = hi;
        hi = nexp2(A2e * segsdt[(d1 * NSEG + s) * 256 + e1]) * hi + segq[(d1 * NSEG + s) * 4096 + en];
    }
}

// ---------------------------------------------------------------------------
// scan phase 1 + gate. cxl returns the last prefetch group's xc values:
// DIR=0 -> cxl[j] = xc[p=8+j]; DIR=1 -> cxl[j] = xc[p=7-j]. The gate reuses
// them (no xc re-load) and is split across both dir-halves.
template <int DIR>
static __device__ __forceinline__ void scan_dir(const float* __restrict__ dt, const float* __restrict__ xc,
                                                int base, int e,
                                                const float (*bms)[16], const float (*cms)[16],
                                                const float* A2, const float* iv,
                                                float* h, float* yreg, float* cxl) {
    float cu[8], cx[8], nu[8], nx[8];
#pragma unroll
    for (int j = 0; j < 8; ++j) {
        const int p = DIR ? (CLh - 1 - j) : j;
        cu[j] = dt[(size_t)(base + p) * 256 + e];
        cx[j] = xc[(size_t)(base + p) * 256 + e];
    }
#pragma unroll
    for (int g = 0; g < CLh / 8; ++g) {
        if (g + 1 < CLh / 8) {
#pragma unroll
            for (int j = 0; j < 8; ++j) {
                const int s = (g + 1) * 8 + j;
                const int p = DIR ? (CLh - 1 - s) : s;
                nu[j] = dt[(size_t)(base + p) * 256 + e];
                nx[j] = xc[(size_t)(base + p) * 256 + e];
            }
        }
#pragma unroll
        for (int j = 0; j < 8; ++j) {
            const int s = g * 8 + j;
            const int p = DIR ? (CLh - 1 - s) : s;
            float u = cu[j], xv = cx[j];
            union { float4 v[4]; float f[16]; } bb, cc;
            const float4* bp = (const float4*)&bms[p][0];
            bb.v[0] = bp[0]; bb.v[1] = bp[1]; bb.v[2] = bp[2]; bb.v[3] = bp[3];
            const float4* cp = (const float4*)&cms[p][0];
            cc.v[0] = cp[0]; cc.v[1] = cp[1]; cc.v[2] = cp[2]; cc.v[3] = cp[3];
            float y = 0.f;
#pragma unroll
            for (int n = 0; n < 16; ++n) {
                float a = nexp2(A2[n] * u);
                float w = xv * bb.f[n] * iv[n];
                h[n] = a * (h[n] + w) - w;
                y += h[n] * cc.f[n];
            }
            yreg[p] = y;
        }
#pragma unroll
        for (int j = 0; j < 8; ++j) { cu[j] = nu[j]; cx[j] = nx[j]; }
    }
#pragma unroll
    for (int j = 0; j < 8; ++j) cxl[j] = cx[j];
}

// CLh=16, grid 512 blocks x 512 thr. NO min-occupancy bound ((512,4) caused a
// 64-VGPR cap -> scratch spills, round 3). Gate split across both dir-halves.
__global__ __launch_bounds__(512) void scan1g_k(const float* __restrict__ dt, const float* __restrict__ xc,
                                                const float* __restrict__ Bm, const float* __restrict__ Cm,
                                                const float* __restrict__ Alog,
                                                const float* __restrict__ Hpp, const float* __restrict__ cumsdtb,
                                                const float* __restrict__ segpre,
                                                const float* __restrict__ sz, const float* __restrict__ Dp,
                                                ushort* __restrict__ AHo, ushort* __restrict__ ALo) {
    const int c = blockIdx.x;
    const int tid = threadIdx.x;
    const int dir = tid >> 8;
    const int e = tid & 255;
    __shared__ float bms[CLh][16];
    __shared__ float cms[CLh][16];
    __shared__ float ysF[8][256];   // yf for l=0..7   (written by dir0)
    __shared__ float ysB[8][256];   // yb for l=8..15  (written by dir1)
    for (int idx = tid; idx < CLh * 16; idx += 512) {
        bms[idx >> 4][idx & 15] = Bm[c * (CLh * 16) + idx];
        cms[idx >> 4][idx & 15] = Cm[c * (CLh * 16) + idx];
    }
    float A2[16], iv[16], h[16];
#pragma unroll
    for (int n = 0; n < 16; ++n) {
        float ea = nexp2(Alog[e * 16 + n] * LOG2E);
        A2[n] = -ea * LOG2E;
        iv[n] = -1.0f / ea;
    }
    // entering state: hp = Hpp + exp2(A2*cum) * segpre
    {
        const int pos = dir ? (NCh - 1 - c) : c;
        const int seg = pos / CPS;
        const float cum = cumsdtb[(dir * NCh + c) * 256 + e];
        const size_t hofs = (size_t)(dir * NCh + c) * 4096 + e * 16;
        const size_t so = (size_t)(dir * NSEG + seg) * 4096 + e * 16;
#pragma unroll
        for (int jj = 0; jj < 4; ++jj) {
            float4 hv = *(const float4*)&Hpp[hofs + 4 * jj];
            float4 sv = *(const float4*)&segpre[so + 4 * jj];
            h[4 * jj + 0] = hv.x + nexp2(A2[4 * jj + 0] * cum) * sv.x;
            h[4 * jj + 1] = hv.y + nexp2(A2[4 * jj + 1] * cum) * sv.y;
            h[4 * jj + 2] = hv.z + nexp2(A2[4 * jj + 2] * cum) * sv.z;
            h[4 * jj + 3] = hv.w + nexp2(A2[4 * jj + 3] * cum) * sv.w;
        }
    }
    const int base = c * CLh;
    float yreg[CLh], cxl[8];
    __syncthreads();
    if (dir == 0) {
        scan_dir<0>(dt, xc, base, e, bms, cms, A2, iv, h, yreg, cxl);
#pragma unroll
        for (int j = 0; j < 8; ++j) ysF[j][e] = yreg[j];
    } else {
        scan_dir<1>(dt, xc, base, e, bms, cms, A2, iv, h, yreg, cxl);
#pragma unroll
        for (int j = 0; j < 8; ++j) ysB[j][e] = yreg[8 + j];
    }
    __syncthreads();
    const float dpv = Dp[e];
    if (dir == 0) {
        // gate l = 8..15 : yf own, yb from LDS, xc from cxl[j]=xc[8+j]
#pragma unroll
        for (int j = 0; j < 8; ++j) {
            const int l = 8 + j;
            size_t gl = (size_t)(base + l) * 256 + e;
            float a = (yreg[l] + ysB[j][e] + dpv * cxl[j]) * sz[gl];
            ushort hh, ll; f2hl(a, &hh, &ll);
            AHo[gl] = hh; ALo[gl] = ll;
        }
    } else {
        // gate l = 7..0 : yb own, yf from LDS, xc from cxl[j]=xc[7-j]
#pragma unroll
        for (int j = 0; j < 8; ++j) {
            const int l = 7 - j;
            size_t gl = (size_t)(base + l) * 256 + e;
            float a = (ysF[l][e] + yreg[l] + dpv * cxl[j]) * sz[gl];
            ushort hh, ll; f2hl(a, &hh, &ll);
            AHo[gl] = hh; ALo[gl] = ll;
        }
    }
}

// ---------------------------------------------------------------------------
// FUSED Wout + unembed. 32-row tile x full 128 cols, K=256 then K=128 through
// LDS (hf never touches global). Grid 256 x 512 threads (8 waves: 2 row x 4 col).
__global__ __launch_bounds__(512) void wu_k(const ushort* __restrict__ AH, const ushort* __restrict__ AL,
                                            const ushort* __restrict__ wH, const ushort* __restrict__ wL,
                                            const float* __restrict__ bout, const float* __restrict__ h_,
                                            const float* __restrict__ pu_b, const float* __restrict__ ks,
                                            float* __restrict__ out) {
    __shared__ __align__(16) char smem[70656];
    ushort (*AsH)[264] = (ushort(*)[264])(smem);            // 32x264x2 = 16896
    ushort (*AsL)[264] = (ushort(*)[264])(smem + 16896);    // ..33792
    ushort (*BsH)[72]  = (ushort(*)[72])(smem + 33792);     // 128x72x2 = 18432
    ushort (*BsL)[72]  = (ushort(*)[72])(smem + 52224);     // ..70656
    ushort (*hfH)[136] = (ushort(*)[136])(smem);            // overlay on As (As dead)
    ushort (*hfL)[136] = (ushort(*)[136])(smem + 8704);     // 32x136x2 = 8704 each

    const int tid = threadIdx.x;
    const int lane = tid & 63, wave = tid >> 6;
    const int wm = wave & 1, wn = wave >> 1;                // rows 2x16, cols 4x32
    const int ln = lane & 15, q = lane >> 4;
    const int mb = blockIdx.x * 32;

    // stage A (AHo/ALo) once for full K=256
    for (int u = tid; u < 1024; u += 512) {
        int r = u >> 5, g = u & 31;
        size_t go = (size_t)(mb + r) * 256 + g * 8;
        *(uint4*)&AsH[r][g * 8] = *(const uint4*)&AH[go];
        *(uint4*)&AsL[r][g * 8] = *(const uint4*)&AL[go];
    }

    f32x4 acc[2];
    acc[0] = (f32x4){0.f, 0.f, 0.f, 0.f};
    acc[1] = (f32x4){0.f, 0.f, 0.f, 0.f};

    // ---- Wout GEMM: hf[32][128] = A[32][256] @ Wout
    for (int kc = 0; kc < 256; kc += 64) {
        __syncthreads();
        for (int u = tid; u < 1024; u += 512) {
            int n = u >> 3, g = u & 7;
            size_t go = (size_t)(W_WOUT) + (size_t)n * 256 + kc + g * 8;
            *(uint4*)&BsH[n][g * 8] = *(const uint4*)&wH[go];
            *(uint4*)&BsL[n][g * 8] = *(const uint4*)&wL[go];
        }
        __syncthreads();
#pragma unroll
        for (int ks_ = 0; ks_ < 64; ks_ += 32) {
            const int kka = kc + ks_ + q * 8;
            const int kkb = ks_ + q * 8;
            bf16x8 ah = *(const bf16x8*)&AsH[wm * 16 + ln][kka];
            bf16x8 al = *(const bf16x8*)&AsL[wm * 16 + ln][kka];
#pragma unroll
            for (int cb = 0; cb < 2; ++cb) {
                bf16x8 bh = *(const bf16x8*)&BsH[wn * 32 + cb * 16 + ln][kkb];
                bf16x8 bl = *(const bf16x8*)&BsL[wn * 32 + cb * 16 + ln][kkb];
                acc[cb] = __builtin_amdgcn_mfma_f32_16x16x32_bf16(ah, bh, acc[cb], 0, 0, 0);
                acc[cb] = __builtin_amdgcn_mfma_f32_16x16x32_bf16(ah, bl, acc[cb], 0, 0, 0);
                acc[cb] = __builtin_amdgcn_mfma_f32_16x16x32_bf16(al, bh, acc[cb], 0, 0, 0);
            }
        }
    }
    __syncthreads();   // As reads done -> safe to overlay hf
    // epilogue 1: + bout + h_ residual -> hf in LDS (hi/lo)
#pragma unroll
    for (int cb = 0; cb < 2; ++cb)
#pragma unroll
        for (int r = 0; r < 4; ++r) {
            int row = wm * 16 + q * 4 + r;
            int col = wn * 32 + cb * 16 + ln;
            float v = acc[cb][r] + bout[col] + h_[(size_t)(mb + row) * 128 + col];
            ushort hh, ll; f2hl(v, &hh, &ll);
            hfH[row][col] = hh;
            hfL[row][col] = ll;
        }
    __syncthreads();

    // ---- unembed GEMM: out[32][128] = hf[32][128] @ pu^T (+pu_b +ks, scattered)
    f32x4 acc2[2];
    acc2[0] = (f32x4){0.f, 0.f, 0.f, 0.f};
    acc2[1] = (f32x4){0.f, 0.f, 0.f, 0.f};
    for (int kc = 0; kc < 128; kc += 64) {
        __syncthreads();
        for (int u = tid; u < 1024; u += 512) {
            int n = u >> 3, g = u & 7;
            size_t go = (size_t)(W_PU) + (size_t)n * 128 + kc + g * 8;
            *(uint4*)&BsH[n][g * 8] = *(const uint4*)&wH[go];
            *(uint4*)&BsL[n][g * 8] = *(const uint4*)&wL[go];
        }
        __syncthreads();
#pragma unroll
        for (int ks_ = 0; ks_ < 64; ks_ += 32) {
            const int kka = kc + ks_ + q * 8;
            const int kkb = ks_ + q * 8;
            bf16x8 ah = *(const bf16x8*)&hfH[wm * 16 + ln][kka];
            bf16x8 al = *(const bf16x8*)&hfL[wm * 16 + ln][kka];
#pragma unroll
            for (int cb = 0; cb < 2; ++cb) {
                bf16x8 bh = *(const bf16x8*)&BsH[wn * 32 + cb * 16 + ln][kkb];
                bf16x8 bl = *(const bf16x8*)&BsL[wn * 32 + cb * 16 + ln][kkb];
                acc2[cb] = __builtin_amdgcn_mfma_f32_16x16x32_bf16(ah, bh, acc2[cb], 0, 0, 0);
                acc2[cb] = __builtin_amdgcn_mfma_f32_16x16x32_bf16(ah, bl, acc2[cb], 0, 0, 0);
                acc2[cb] = __builtin_amdgcn_mfma_f32_16x16x32_bf16(al, bh, acc2[cb], 0, 0, 0);
            }
        }
    }
#pragma unroll
    for (int cb = 0; cb < 2; ++cb)
#pragma unroll
        for (int r = 0; r < 4; ++r) {
            int l = mb + wm * 16 + q * 4 + r;
            int col = wn * 32 + cb * 16 + ln;
            int xg = l >> 8, yg = (l >> 3) & 31, zg = l & 7;
            int cch = col >> 3, ijk = col & 7;
            int i2 = (ijk >> 2) & 1, j2 = (ijk >> 1) & 1, k2 = ijk & 1;
            size_t idx = (size_t)((cch * 64 + 2 * xg + i2) * 64 + (2 * yg + j2)) * 16 + 2 * zg + k2;
            out[idx] = acc2[cb][r] + pu_b[cch] + ks[idx];
        }
}

// ---------------------------------------------------------------------------
extern "C" void kernel_launch(void* const* d_in, const int* in_sizes, int n_in,
                              void* d_out, int out_size, void* d_ws, size_t ws_size,
                              hipStream_t stream) {
    const float* ks    = (const float*)d_in[0];
    const float* mask  = (const float*)d_in[1];
    const float* pe_w  = (const float*)d_in[2];
    const float* pe_b  = (const float*)d_in[3];
    const float* pu_w  = (const float*)d_in[4];
    const float* pu_b  = (const float*)d_in[5];
    const float* ln_g  = (const float*)d_in[6];
    const float* ln_b  = (const float*)d_in[7];
    const float* fn_g  = (const float*)d_in[8];
    const float* fn_b  = (const float*)d_in[9];
    const float* cond_band = (const float*)d_in[10];
    const float* cond_rad  = (const float*)d_in[11];
    const float* cond_mask = (const float*)d_in[12];
    const float* Win   = (const float*)d_in[13];
    const float* bin_  = (const float*)d_in[14];
    const float* convw = (const float*)d_in[15];
    const float* convb = (const float*)d_in[16];
    const float* Wx    = (const float*)d_in[17];
    const float* Wdt   = (const float*)d_in[18];
    const float* bdt   = (const float*)d_in[19];
    const float* Alog  = (const float*)d_in[20];
    const float* Dp    = (const float*)d_in[21];
    const float* Wout  = (const float*)d_in[22];
    const float* bout  = (const float*)d_in[23];
    const float* edt   = (const float*)d_in[24];
    const float* eB    = (const float*)d_in[25];
    const float* eC    = (const float*)d_in[26];
    const float* wr    = (const float*)d_in[27];
    const float* wm    = (const float*)d_in[28];
    float* out = (float*)d_out;

    char* base = (char*)d_ws;
    size_t o = 0;
    auto alloc = [&](size_t bytes) { char* p = base + o; o += (bytes + 255) & ~(size_t)255; return p; };
    float*  mbuf = (float*)alloc(32768);
    ushort* wH   = (ushort*)alloc(W_TOT * 2);
    ushort* wL   = (ushort*)alloc(W_TOT * 2);
    float*  h_   = (float*)alloc(4194304);
    ushort* hnH  = (ushort*)alloc(2097152);
    ushort* hnL  = (ushort*)alloc(2097152);
    float*  xp   = (float*)alloc(8388608);
    float*  sz   = (float*)alloc(8388608);
    float*  xc   = (float*)alloc(8388608);
    float*  dt   = (float*)alloc(8388608);
    float*  Bm   = (float*)alloc(524288);
    float*  Cm   = (float*)alloc(524288);
    float*  Hb   = (float*)alloc((size_t)2 * NCh * 4096 * 4);    // 16 MB
    float*  Hpp  = (float*)alloc((size_t)2 * NCh * 4096 * 4);    // 16 MB
    float*  sdtb = (float*)alloc((size_t)NCh * 256 * 4);         // 512 KB
    float*  cumsdtb = (float*)alloc((size_t)2 * NCh * 256 * 4);  // 1 MB
    float*  segq    = (float*)alloc((size_t)2 * NSEG * 4096 * 4);
    float*  segsdt  = (float*)alloc((size_t)2 * NSEG * 256 * 4);
    float*  segpre  = (float*)alloc((size_t)2 * NSEG * 4096 * 4);
    ushort* AHo  = (ushort*)alloc(4194304);
    ushort* ALo  = (ushort*)alloc(4194304);

    embed_ln_k<<<1376, 256, 0, stream>>>(ks, pe_w, Win, Wx, Wdt, Wout, pu_w, mask,
                                         pe_b, cond_band, cond_rad, cond_mask,
                                         ln_g, ln_b, fn_g, fn_b,
                                         wH, wL, mbuf, h_, hnH, hnL);
    win_k<<<dim3(128, 8), 256, 0, stream>>>(hnH, hnL, wH, wL, bin_, xp, sz);
    proj_k<<<256, 512, 0, stream>>>(xp, convw, convb, wH, wL, bdt, mbuf, edt, eB, eC, wr, wm,
                                    xc, dt, Bm, Cm);
    scan0_k<<<NCh, 512, 0, stream>>>(dt, xc, Bm, Alog, Hb, sdtb);
    combine1_k<<<256, 256, 0, stream>>>(Hb, sdtb, Alog, Hpp, cumsdtb, segq, segsdt);
    combine2_k<<<128, 64, 0, stream>>>(segq, segsdt, Alog, segpre);
    scan1g_k<<<NCh, 512, 0, stream>>>(dt, xc, Bm, Cm, Alog, Hpp, cumsdtb, segpre, sz, Dp, AHo, ALo);
    wu_k<<<256, 512, 0, stream>>>(AHo, ALo, wH, wL, bout, h_, pu_b, ks, out);
}